// Round 2
// baseline (5590.616 us; speedup 1.0000x reference)
//
#include <hip/hip_runtime.h>
#include <hip/hip_bf16.h>

#define EPS 1e-5f

// ---------------------------------------------------------------------------
// K1: integer degree histograms (atomic-bound: ~23G atomics/s memory-side RMW)
__global__ void degrees_kernel(const int* __restrict__ src, const int* __restrict__ dst,
                               int* __restrict__ outdeg, int* __restrict__ indeg, int E) {
    int i = blockIdx.x * blockDim.x + threadIdx.x;
    if (i < E) {
        atomicAdd(&outdeg[src[i]], 1);
        atomicAdd(&indeg[dst[i]], 1);
    }
}

// K2: normalization factors rsqrt(max(deg,1))
__global__ void norms_kernel(const int* __restrict__ outdeg, const int* __restrict__ indeg,
                             float* __restrict__ nsrc, float* __restrict__ ndst, int n) {
    int i = blockIdx.x * blockDim.x + threadIdx.x;
    if (i < n) {
        nsrc[i] = rsqrtf((float)max(outdeg[i], 1));
        ndst[i] = rsqrtf((float)max(indeg[i], 1));
    }
}

// ---------------------------------------------------------------------------
// Multi-block exclusive scan of in-degrees -> CSC offsets.
// K3a: per-block (1024-elem) sums
__global__ __launch_bounds__(256) void scan_partial_kernel(const int* __restrict__ deg,
                                                           int* __restrict__ bsums, int n) {
    __shared__ int wsum[4];
    const int tid = threadIdx.x, lane = tid & 63, wid = tid >> 6;
    const int i0 = blockIdx.x * 1024 + tid * 4;
    int s = 0;
    if (i0 + 3 < n) {
        int4 v = *(const int4*)(deg + i0);
        s = v.x + v.y + v.z + v.w;
    } else {
        for (int j = 0; j < 4; ++j) if (i0 + j < n) s += deg[i0 + j];
    }
    #pragma unroll
    for (int off = 32; off >= 1; off >>= 1) s += __shfl_down(s, off, 64);
    if (lane == 0) wsum[wid] = s;
    __syncthreads();
    if (tid == 0) bsums[blockIdx.x] = wsum[0] + wsum[1] + wsum[2] + wsum[3];
}

// K3b: single-wave exclusive scan of block sums (nb <= 64), writes offs[n]=total
__global__ __launch_bounds__(64) void scan_bsums_kernel(int* __restrict__ bsums,
                                                        int* __restrict__ offs, int nb, int n) {
    int lane = threadIdx.x;
    int v = (lane < nb) ? bsums[lane] : 0;
    int x = v;
    #pragma unroll
    for (int off = 1; off < 64; off <<= 1) {
        int t = __shfl_up(x, off, 64);
        if (lane >= off) x += t;
    }
    if (lane < nb) bsums[lane] = x - v;   // exclusive
    if (lane == 63) offs[n] = x;          // grand total
}

// K3c: per-block exclusive scan + add block prefix
__global__ __launch_bounds__(256) void scan_final_kernel(const int* __restrict__ deg,
                                                         const int* __restrict__ bsums,
                                                         int* __restrict__ offs, int n) {
    __shared__ int wsum[4];
    const int tid = threadIdx.x, lane = tid & 63, wid = tid >> 6;
    const int i0 = blockIdx.x * 1024 + tid * 4;
    int d0 = 0, d1 = 0, d2 = 0, d3 = 0;
    if (i0 + 3 < n) {
        int4 v = *(const int4*)(deg + i0);
        d0 = v.x; d1 = v.y; d2 = v.z; d3 = v.w;
    } else {
        if (i0 + 0 < n) d0 = deg[i0 + 0];
        if (i0 + 1 < n) d1 = deg[i0 + 1];
        if (i0 + 2 < n) d2 = deg[i0 + 2];
        if (i0 + 3 < n) d3 = deg[i0 + 3];
    }
    int s = d0 + d1 + d2 + d3;
    int x = s;
    #pragma unroll
    for (int off = 1; off < 64; off <<= 1) {
        int t = __shfl_up(x, off, 64);
        if (lane >= off) x += t;
    }
    if (lane == 63) wsum[wid] = x;
    __syncthreads();
    int wpre = 0;
    #pragma unroll
    for (int w = 0; w < 4; ++w) if (w < wid) wpre += wsum[w];
    int base = bsums[blockIdx.x] + wpre + (x - s);
    if (i0 + 0 < n) offs[i0 + 0] = base;
    if (i0 + 1 < n) offs[i0 + 1] = base + d0;
    if (i0 + 2 < n) offs[i0 + 2] = base + d0 + d1;
    if (i0 + 3 < n) offs[i0 + 3] = base + d0 + d1 + d2;
}

// K4: scatter edges into CSC slots (order within node nondeterministic; only
// perturbs fp32 sum order, ~1e-6 effect)
__global__ void fill_csc_kernel(const int* __restrict__ src, const int* __restrict__ dst,
                                const int* __restrict__ offs, int* __restrict__ cursor,
                                int* __restrict__ csc, int E) {
    int i = blockIdx.x * blockDim.x + threadIdx.x;
    if (i < E) {
        int d = dst[i];
        int p = atomicAdd(&cursor[d], 1);
        csc[offs[d] + p] = src[i];
    }
}

// ---------------------------------------------------------------------------
// K5: fp32 GEMM  C[M,128] (=|+=) (A[M,128] * rowscale) @ B[128,128] (+ colbias)
// 256 threads, 64x64 tile (grid.y=2 col halves), 4x4 micro-tile, k-quad float4
// inner loop: per 4 k-steps 8x ds_read_b128 + 64 FMA per thread -> VALU-bound.
__global__ __launch_bounds__(256) void gemm128_kernel(
    const float* __restrict__ A, const float* __restrict__ B, float* __restrict__ C,
    const float* __restrict__ rowscale, const float* __restrict__ colbias,
    int M, int accumulate) {
    __shared__ __align__(16) float As[64][132];   // 528B pitch: 16B-aligned rows
    __shared__ __align__(16) float Bs[128][64];
    const int row0 = blockIdx.x * 64;
    const int cb = blockIdx.y;
    const int tid = threadIdx.x;

    {   // stage B column-half: 128x64
        const float* Bsrc = B + cb * 64;
        for (int idx = tid; idx < 128 * 16; idx += 256) {
            int k = idx >> 4;
            int j = (idx & 15) << 2;
            *(float4*)&Bs[k][j] = *(const float4*)(Bsrc + k * 128 + j);
        }
    }
    {   // stage A tile 64x128, fused row-scale
        for (int idx = tid; idx < 64 * 32; idx += 256) {
            int m = idx >> 5;
            int j = (idx & 31) << 2;
            int row = row0 + m;
            float4 v = make_float4(0.f, 0.f, 0.f, 0.f);
            float s = 1.0f;
            if (row < M) {
                v = *(const float4*)(A + (size_t)row * 128 + j);
                if (rowscale) s = rowscale[row];
            }
            *(float4*)&As[m][j] = make_float4(v.x * s, v.y * s, v.z * s, v.w * s);
        }
    }
    __syncthreads();

    const int tx = tid & 15;
    const int ty = tid >> 4;
    const int r0 = ty * 4;
    float acc[4][4] = {};
    #pragma unroll
    for (int k0 = 0; k0 < 128; k0 += 4) {
        float4 a0 = *(const float4*)&As[r0 + 0][k0];
        float4 a1 = *(const float4*)&As[r0 + 1][k0];
        float4 a2 = *(const float4*)&As[r0 + 2][k0];
        float4 a3 = *(const float4*)&As[r0 + 3][k0];
        float4 b0 = *(const float4*)&Bs[k0 + 0][tx * 4];
        float4 b1 = *(const float4*)&Bs[k0 + 1][tx * 4];
        float4 b2 = *(const float4*)&Bs[k0 + 2][tx * 4];
        float4 b3 = *(const float4*)&Bs[k0 + 3][tx * 4];
        acc[0][0] += a0.x*b0.x + a0.y*b1.x + a0.z*b2.x + a0.w*b3.x;
        acc[0][1] += a0.x*b0.y + a0.y*b1.y + a0.z*b2.y + a0.w*b3.y;
        acc[0][2] += a0.x*b0.z + a0.y*b1.z + a0.z*b2.z + a0.w*b3.z;
        acc[0][3] += a0.x*b0.w + a0.y*b1.w + a0.z*b2.w + a0.w*b3.w;
        acc[1][0] += a1.x*b0.x + a1.y*b1.x + a1.z*b2.x + a1.w*b3.x;
        acc[1][1] += a1.x*b0.y + a1.y*b1.y + a1.z*b2.y + a1.w*b3.y;
        acc[1][2] += a1.x*b0.z + a1.y*b1.z + a1.z*b2.z + a1.w*b3.z;
        acc[1][3] += a1.x*b0.w + a1.y*b1.w + a1.z*b2.w + a1.w*b3.w;
        acc[2][0] += a2.x*b0.x + a2.y*b1.x + a2.z*b2.x + a2.w*b3.x;
        acc[2][1] += a2.x*b0.y + a2.y*b1.y + a2.z*b2.y + a2.w*b3.y;
        acc[2][2] += a2.x*b0.z + a2.y*b1.z + a2.z*b2.z + a2.w*b3.z;
        acc[2][3] += a2.x*b0.w + a2.y*b1.w + a2.z*b2.w + a2.w*b3.w;
        acc[3][0] += a3.x*b0.x + a3.y*b1.x + a3.z*b2.x + a3.w*b3.x;
        acc[3][1] += a3.x*b0.y + a3.y*b1.y + a3.z*b2.y + a3.w*b3.y;
        acc[3][2] += a3.x*b0.z + a3.y*b1.z + a3.z*b2.z + a3.w*b3.z;
        acc[3][3] += a3.x*b0.w + a3.y*b1.w + a3.z*b2.w + a3.w*b3.w;
    }

    const int colbase = cb * 64 + tx * 4;
    float4 bias = make_float4(0.f, 0.f, 0.f, 0.f);
    if (colbias) bias = *(const float4*)(colbias + colbase);
    #pragma unroll
    for (int i = 0; i < 4; ++i) {
        int row = row0 + r0 + i;
        if (row < M) {
            float* cp = C + (size_t)row * 128 + colbase;
            float4 r = make_float4(acc[i][0] + bias.x, acc[i][1] + bias.y,
                                   acc[i][2] + bias.z, acc[i][3] + bias.w);
            if (accumulate) {
                float4 old = *(float4*)cp;
                r.x += old.x; r.y += old.y; r.z += old.z; r.w += old.w;
            }
            *(float4*)cp = r;
        }
    }
}

// ---------------------------------------------------------------------------
// K6: CSC aggregation + norm_dst + (bias) + BN + ReLU. One wave per dst node,
// float2/lane = full 512B row per gather, 4-deep unroll for MLP.
__global__ __launch_bounds__(256) void aggregate_kernel(
    const float* __restrict__ hw, const int* __restrict__ offs, const int* __restrict__ csc,
    const float* __restrict__ norm_dst, const float* __restrict__ bias,
    const float* __restrict__ gamma, const float* __restrict__ beta,
    const float* __restrict__ mean, const float* __restrict__ var,
    float* __restrict__ hout, int n) {
    const int lane = threadIdx.x & 63;
    const int gw = (blockIdx.x * blockDim.x + threadIdx.x) >> 6;
    const int nw = (gridDim.x * blockDim.x) >> 6;
    const int c = lane * 2;

    const float sc0 = gamma[c] * rsqrtf(var[c] + EPS);
    const float sc1 = gamma[c + 1] * rsqrtf(var[c + 1] + EPS);
    const float mn0 = mean[c], mn1 = mean[c + 1];
    const float bt0 = beta[c], bt1 = beta[c + 1];
    const float bi0 = bias ? bias[c] : 0.f;
    const float bi1 = bias ? bias[c + 1] : 0.f;

    for (int v = gw; v < n; v += nw) {
        int e0 = offs[v], e1 = offs[v + 1];
        float2 acc = make_float2(0.f, 0.f);
        int e = e0;
        for (; e + 4 <= e1; e += 4) {
            int s0 = csc[e], s1 = csc[e + 1], s2 = csc[e + 2], s3 = csc[e + 3];
            float2 p0 = *(const float2*)(hw + (size_t)s0 * 128 + c);
            float2 p1 = *(const float2*)(hw + (size_t)s1 * 128 + c);
            float2 p2 = *(const float2*)(hw + (size_t)s2 * 128 + c);
            float2 p3 = *(const float2*)(hw + (size_t)s3 * 128 + c);
            acc.x += (p0.x + p1.x) + (p2.x + p3.x);
            acc.y += (p0.y + p1.y) + (p2.y + p3.y);
        }
        for (; e < e1; ++e) {
            int s0 = csc[e];
            float2 p0 = *(const float2*)(hw + (size_t)s0 * 128 + c);
            acc.x += p0.x; acc.y += p0.y;
        }
        float nd = norm_dst[v];
        float h0 = acc.x * nd + bi0;
        float h1 = acc.y * nd + bi1;
        h0 = fmaxf((h0 - mn0) * sc0 + bt0, 0.f);
        h1 = fmaxf((h1 - mn1) * sc1 + bt1, 0.f);
        *(float2*)(hout + (size_t)v * 128 + c) = make_float2(h0, h1);
    }
}

// ---------------------------------------------------------------------------
// K7: final classifier: z = relu(BN0(cls_acc)); out = z @ W1 + b1
__global__ __launch_bounds__(256) void classifier_final_kernel(
    const float* __restrict__ acc,
    const float* __restrict__ g, const float* __restrict__ bt,
    const float* __restrict__ mn, const float* __restrict__ vr,
    const float* __restrict__ W1, const float* __restrict__ b1,
    float* __restrict__ out, int n) {
    __shared__ float W1s[128 * 47];
    __shared__ float zbuf[4][128];
    const int tid = threadIdx.x, lane = tid & 63, wid = tid >> 6;
    for (int idx = tid; idx < 128 * 47; idx += 256) W1s[idx] = W1[idx];
    __syncthreads();

    const int c0 = lane * 2;
    const float sc0 = g[c0] * rsqrtf(vr[c0] + EPS);
    const float sc1 = g[c0 + 1] * rsqrtf(vr[c0 + 1] + EPS);
    const float m0 = mn[c0], m1 = mn[c0 + 1];
    const float be0 = bt[c0], be1 = bt[c0 + 1];
    const float bb = (lane < 47) ? b1[lane] : 0.f;

    const int gw = blockIdx.x * 4 + wid;
    const int nw = gridDim.x * 4;
    for (int row = gw; row < n; row += nw) {
        float2 a = *(const float2*)(acc + (size_t)row * 128 + c0);
        zbuf[wid][c0]     = fmaxf((a.x - m0) * sc0 + be0, 0.f);
        zbuf[wid][c0 + 1] = fmaxf((a.y - m1) * sc1 + be1, 0.f);
        float o = 0.f;
        if (lane < 47) {
            #pragma unroll 8
            for (int k = 0; k < 128; ++k) o += zbuf[wid][k] * W1s[k * 47 + lane];
            out[(size_t)row * 47 + lane] = o + bb;
        }
    }
}

// ---------------------------------------------------------------------------
extern "C" void kernel_launch(void* const* d_in, const int* in_sizes, int n_in,
                              void* d_out, int out_size, void* d_ws, size_t ws_size,
                              hipStream_t stream) {
    const float* feat     = (const float*)d_in[0];
    const int*   src      = (const int*)d_in[1];
    const int*   dst      = (const int*)d_in[2];
    const float* enc_W    = (const float*)d_in[3];
    const float* enc_bias = (const float*)d_in[4];
    const float* bn_gamma = (const float*)d_in[5];
    const float* bn_beta  = (const float*)d_in[6];
    const float* bn_mean  = (const float*)d_in[7];
    const float* bn_var   = (const float*)d_in[8];
    const float* cls_W0   = (const float*)d_in[9];
    const float* cls_b0   = (const float*)d_in[10];
    const float* cls_g0   = (const float*)d_in[11];
    const float* cls_be0  = (const float*)d_in[12];
    const float* cls_m0   = (const float*)d_in[13];
    const float* cls_v0   = (const float*)d_in[14];
    const float* cls_W1   = (const float*)d_in[15];
    const float* cls_b1   = (const float*)d_in[16];
    float* out = (float*)d_out;

    const int N_ = in_sizes[0] / 128;
    const int E_ = in_sizes[1];

    char* p = (char*)d_ws;
    auto alloc = [&](size_t bytes) {
        char* r = p;
        p += (bytes + 255) & ~(size_t)255;
        return r;
    };
    float* h_a      = (float*)alloc((size_t)N_ * 128 * 4);
    float* h_b      = (float*)alloc((size_t)N_ * 128 * 4);
    float* cls_acc  = (float*)alloc((size_t)N_ * 128 * 4);
    float* norm_src = (float*)alloc((size_t)N_ * 4);
    float* norm_dst = (float*)alloc((size_t)N_ * 4);
    int* outdeg     = (int*)alloc((size_t)N_ * 4);
    int* indeg      = (int*)alloc((size_t)N_ * 4);
    int* cursor     = (int*)alloc((size_t)N_ * 4);
    int* offs       = (int*)alloc((size_t)(N_ + 1) * 4);
    int* csc        = (int*)alloc((size_t)E_ * 4);
    int* bsums      = (int*)alloc(256 * 4);

    hipMemsetAsync(outdeg, 0, (size_t)N_ * 4, stream);
    hipMemsetAsync(indeg, 0, (size_t)N_ * 4, stream);
    hipMemsetAsync(cursor, 0, (size_t)N_ * 4, stream);

    const int eb = (E_ + 255) / 256;
    const int nb = (N_ + 1023) / 1024;   // 49 blocks for N=50000 (<=64 required)
    degrees_kernel<<<eb, 256, 0, stream>>>(src, dst, outdeg, indeg, E_);
    norms_kernel<<<(N_ + 255) / 256, 256, 0, stream>>>(outdeg, indeg, norm_src, norm_dst, N_);
    scan_partial_kernel<<<nb, 256, 0, stream>>>(indeg, bsums, N_);
    scan_bsums_kernel<<<1, 64, 0, stream>>>(bsums, offs, nb, N_);
    scan_final_kernel<<<nb, 256, 0, stream>>>(indeg, bsums, offs, N_);
    fill_csc_kernel<<<eb, 256, 0, stream>>>(src, dst, offs, cursor, csc, E_);

    dim3 ggrid((N_ + 63) / 64, 2);
    const int agg_blocks = (N_ + 3) / 4;

    for (int i = 0; i < 4; ++i) {
        const float* hin = (i == 0) ? feat : h_a;
        gemm128_kernel<<<ggrid, 256, 0, stream>>>(
            hin, enc_W + (size_t)i * 128 * 128, h_b, norm_src, nullptr, N_, 0);
        aggregate_kernel<<<agg_blocks, 256, 0, stream>>>(
            h_b, offs, csc, norm_dst,
            (i == 3) ? enc_bias : nullptr,
            bn_gamma + i * 128, bn_beta + i * 128, bn_mean + i * 128, bn_var + i * 128,
            h_a, N_);
        gemm128_kernel<<<ggrid, 256, 0, stream>>>(
            h_a, cls_W0 + (size_t)i * 128 * 128, cls_acc, nullptr,
            (i == 0) ? cls_b0 : nullptr, N_, (i == 0) ? 0 : 1);
    }
    classifier_final_kernel<<<(N_ + 15) / 16, 256, 0, stream>>>(
        cls_acc, cls_g0, cls_be0, cls_m0, cls_v0, cls_W1, cls_b1, out, N_);
}

// Round 3
// 623.236 us; speedup vs baseline: 8.9703x; 8.9703x over previous
//
#include <hip/hip_runtime.h>
#include <hip/hip_bf16.h>

#define EPS 1e-5f

// ---------------------------------------------------------------------------
// K1: degree histograms; also emits rank[i] = arrival order of edge i at its
// dst node (old value of the atomic) so fill_csc needs no cursor atomics.
__global__ void degrees_kernel(const int* __restrict__ src, const int* __restrict__ dst,
                               int* __restrict__ outdeg, int* __restrict__ indeg,
                               int* __restrict__ rank, int E) {
    int i = blockIdx.x * blockDim.x + threadIdx.x;
    if (i < E) {
        atomicAdd(&outdeg[src[i]], 1);
        rank[i] = atomicAdd(&indeg[dst[i]], 1);
    }
}

// K2: normalization factors rsqrt(max(deg,1))
__global__ void norms_kernel(const int* __restrict__ outdeg, const int* __restrict__ indeg,
                             float* __restrict__ nsrc, float* __restrict__ ndst, int n) {
    int i = blockIdx.x * blockDim.x + threadIdx.x;
    if (i < n) {
        nsrc[i] = rsqrtf((float)max(outdeg[i], 1));
        ndst[i] = rsqrtf((float)max(indeg[i], 1));
    }
}

// ---------------------------------------------------------------------------
// Multi-block exclusive scan of in-degrees -> CSC offsets.
__global__ __launch_bounds__(256) void scan_partial_kernel(const int* __restrict__ deg,
                                                           int* __restrict__ bsums, int n) {
    __shared__ int wsum[4];
    const int tid = threadIdx.x, lane = tid & 63, wid = tid >> 6;
    const int i0 = blockIdx.x * 1024 + tid * 4;
    int s = 0;
    if (i0 + 3 < n) {
        int4 v = *(const int4*)(deg + i0);
        s = v.x + v.y + v.z + v.w;
    } else {
        for (int j = 0; j < 4; ++j) if (i0 + j < n) s += deg[i0 + j];
    }
    #pragma unroll
    for (int off = 32; off >= 1; off >>= 1) s += __shfl_down(s, off, 64);
    if (lane == 0) wsum[wid] = s;
    __syncthreads();
    if (tid == 0) bsums[blockIdx.x] = wsum[0] + wsum[1] + wsum[2] + wsum[3];
}

__global__ __launch_bounds__(64) void scan_bsums_kernel(int* __restrict__ bsums,
                                                        int* __restrict__ offs, int nb, int n) {
    int lane = threadIdx.x;
    int v = (lane < nb) ? bsums[lane] : 0;
    int x = v;
    #pragma unroll
    for (int off = 1; off < 64; off <<= 1) {
        int t = __shfl_up(x, off, 64);
        if (lane >= off) x += t;
    }
    if (lane < nb) bsums[lane] = x - v;
    if (lane == 63) offs[n] = x;
}

__global__ __launch_bounds__(256) void scan_final_kernel(const int* __restrict__ deg,
                                                         const int* __restrict__ bsums,
                                                         int* __restrict__ offs, int n) {
    __shared__ int wsum[4];
    const int tid = threadIdx.x, lane = tid & 63, wid = tid >> 6;
    const int i0 = blockIdx.x * 1024 + tid * 4;
    int d0 = 0, d1 = 0, d2 = 0, d3 = 0;
    if (i0 + 3 < n) {
        int4 v = *(const int4*)(deg + i0);
        d0 = v.x; d1 = v.y; d2 = v.z; d3 = v.w;
    } else {
        if (i0 + 0 < n) d0 = deg[i0 + 0];
        if (i0 + 1 < n) d1 = deg[i0 + 1];
        if (i0 + 2 < n) d2 = deg[i0 + 2];
        if (i0 + 3 < n) d3 = deg[i0 + 3];
    }
    int s = d0 + d1 + d2 + d3;
    int x = s;
    #pragma unroll
    for (int off = 1; off < 64; off <<= 1) {
        int t = __shfl_up(x, off, 64);
        if (lane >= off) x += t;
    }
    if (lane == 63) wsum[wid] = x;
    __syncthreads();
    int wpre = 0;
    #pragma unroll
    for (int w = 0; w < 4; ++w) if (w < wid) wpre += wsum[w];
    int base = bsums[blockIdx.x] + wpre + (x - s);
    if (i0 + 0 < n) offs[i0 + 0] = base;
    if (i0 + 1 < n) offs[i0 + 1] = base + d0;
    if (i0 + 2 < n) offs[i0 + 2] = base + d0 + d1;
    if (i0 + 3 < n) offs[i0 + 3] = base + d0 + d1 + d2;
}

// K4: pure scatter using precomputed ranks (no atomics)
__global__ void fill_csc_kernel(const int* __restrict__ src, const int* __restrict__ dst,
                                const int* __restrict__ offs, const int* __restrict__ rank,
                                int* __restrict__ csc, int E) {
    int i = blockIdx.x * blockDim.x + threadIdx.x;
    if (i < E) csc[offs[dst[i]] + rank[i]] = src[i];
}

// ---------------------------------------------------------------------------
// K5: fp32 GEMM  C[M,128] (=|+=) (A[M,128]*rowscale) @ B[128,128] (+ colbias)
// 256 threads, 128x128 tile, K-chunks of 64, transposed-A LDS, 8x8 microtile
// (rows r0/r0+64, cols c0/c0+64). LDS:VALU cycle ratio = 1.5 (per-wave kstep:
// 4x ds_read_b128 = 48 cyc LDS-pipe vs 64 FMA = 128 SIMD-cyc).
__global__ __launch_bounds__(256) void gemm128_kernel(
    const float* __restrict__ A, const float* __restrict__ B, float* __restrict__ C,
    const float* __restrict__ rowscale, const float* __restrict__ colbias,
    int M, int accumulate) {
    __shared__ __align__(16) float At[64][128];   // At[k][m], 32 KB
    __shared__ __align__(16) float Bs[64][128];   // Bs[k][j], 32 KB
    const int row0 = blockIdx.x * 128;
    const int tid = threadIdx.x;
    const int tx = tid & 15;          // col group
    const int ty = tid >> 4;          // row group
    const int c0 = tx * 4;            // cols c0..c0+3 and c0+64..c0+67
    const int r0 = ty * 4;            // rows r0..r0+3 and r0+64..r0+67

    // per-thread A-staging constants (mapping: m = tid&127, kq = (tid>>7)+2*it)
    const int ma = tid & 127;
    const int kq0 = tid >> 7;
    const int rowa = row0 + ma;
    const bool rok = (rowa < M);
    const float sa = (rok && rowscale) ? rowscale[rowa] : 1.0f;
    const float* Arow = A + (size_t)rowa * 128;

    float acc[8][8];
    #pragma unroll
    for (int i = 0; i < 8; ++i)
        #pragma unroll
        for (int j = 0; j < 8; ++j) acc[i][j] = 0.f;

    for (int kc = 0; kc < 128; kc += 64) {
        // stage B chunk 64x128 (coalesced float4)
        #pragma unroll
        for (int s = 0; s < 8; ++s) {
            int idx = tid + s * 256;
            int k = idx >> 5;
            int j = (idx & 31) << 2;
            *(float4*)&Bs[k][j] = *(const float4*)(B + (size_t)(kc + k) * 128 + j);
        }
        // stage A chunk transposed (+rowscale); L1 absorbs the strided reads
        #pragma unroll
        for (int it = 0; it < 8; ++it) {
            int k = (kq0 + 2 * it) * 4;
            float4 v = make_float4(0.f, 0.f, 0.f, 0.f);
            if (rok) v = *(const float4*)(Arow + kc + k);
            At[k + 0][ma] = v.x * sa;
            At[k + 1][ma] = v.y * sa;
            At[k + 2][ma] = v.z * sa;
            At[k + 3][ma] = v.w * sa;
        }
        __syncthreads();

        #pragma unroll 4
        for (int k = 0; k < 64; ++k) {
            float4 aL = *(const float4*)&At[k][r0];
            float4 aH = *(const float4*)&At[k][r0 + 64];
            float4 bL = *(const float4*)&Bs[k][c0];
            float4 bH = *(const float4*)&Bs[k][c0 + 64];
            float a[8] = {aL.x, aL.y, aL.z, aL.w, aH.x, aH.y, aH.z, aH.w};
            float b[8] = {bL.x, bL.y, bL.z, bL.w, bH.x, bH.y, bH.z, bH.w};
            #pragma unroll
            for (int i = 0; i < 8; ++i)
                #pragma unroll
                for (int j = 0; j < 8; ++j) acc[i][j] += a[i] * b[j];
        }
        __syncthreads();
    }

    // epilogue
    float4 biasL = make_float4(0.f, 0.f, 0.f, 0.f);
    float4 biasH = make_float4(0.f, 0.f, 0.f, 0.f);
    if (colbias) {
        biasL = *(const float4*)(colbias + c0);
        biasH = *(const float4*)(colbias + c0 + 64);
    }
    #pragma unroll
    for (int i = 0; i < 8; ++i) {
        int row = row0 + ((i < 4) ? (r0 + i) : (64 + r0 + i - 4));
        if (row < M) {
            float* cpL = C + (size_t)row * 128 + c0;
            float* cpH = cpL + 64;
            float4 rL = make_float4(acc[i][0] + biasL.x, acc[i][1] + biasL.y,
                                    acc[i][2] + biasL.z, acc[i][3] + biasL.w);
            float4 rH = make_float4(acc[i][4] + biasH.x, acc[i][5] + biasH.y,
                                    acc[i][6] + biasH.z, acc[i][7] + biasH.w);
            if (accumulate) {
                float4 oL = *(float4*)cpL;
                float4 oH = *(float4*)cpH;
                rL.x += oL.x; rL.y += oL.y; rL.z += oL.z; rL.w += oL.w;
                rH.x += oH.x; rH.y += oH.y; rH.z += oH.z; rH.w += oH.w;
            }
            *(float4*)cpL = rL;
            *(float4*)cpH = rH;
        }
    }
}

// ---------------------------------------------------------------------------
// K6: CSC aggregation + norm_dst + (bias) + BN + ReLU. One wave per dst node.
__global__ __launch_bounds__(256) void aggregate_kernel(
    const float* __restrict__ hw, const int* __restrict__ offs, const int* __restrict__ csc,
    const float* __restrict__ norm_dst, const float* __restrict__ bias,
    const float* __restrict__ gamma, const float* __restrict__ beta,
    const float* __restrict__ mean, const float* __restrict__ var,
    float* __restrict__ hout, int n) {
    const int lane = threadIdx.x & 63;
    const int gw = (blockIdx.x * blockDim.x + threadIdx.x) >> 6;
    const int nw = (gridDim.x * blockDim.x) >> 6;
    const int c = lane * 2;

    const float sc0 = gamma[c] * rsqrtf(var[c] + EPS);
    const float sc1 = gamma[c + 1] * rsqrtf(var[c + 1] + EPS);
    const float mn0 = mean[c], mn1 = mean[c + 1];
    const float bt0 = beta[c], bt1 = beta[c + 1];
    const float bi0 = bias ? bias[c] : 0.f;
    const float bi1 = bias ? bias[c + 1] : 0.f;

    for (int v = gw; v < n; v += nw) {
        int e0 = offs[v], e1 = offs[v + 1];
        float2 acc = make_float2(0.f, 0.f);
        int e = e0;
        for (; e + 4 <= e1; e += 4) {
            int s0 = csc[e], s1 = csc[e + 1], s2 = csc[e + 2], s3 = csc[e + 3];
            float2 p0 = *(const float2*)(hw + (size_t)s0 * 128 + c);
            float2 p1 = *(const float2*)(hw + (size_t)s1 * 128 + c);
            float2 p2 = *(const float2*)(hw + (size_t)s2 * 128 + c);
            float2 p3 = *(const float2*)(hw + (size_t)s3 * 128 + c);
            acc.x += (p0.x + p1.x) + (p2.x + p3.x);
            acc.y += (p0.y + p1.y) + (p2.y + p3.y);
        }
        for (; e < e1; ++e) {
            int s0 = csc[e];
            float2 p0 = *(const float2*)(hw + (size_t)s0 * 128 + c);
            acc.x += p0.x; acc.y += p0.y;
        }
        float nd = norm_dst[v];
        float h0 = acc.x * nd + bi0;
        float h1 = acc.y * nd + bi1;
        h0 = fmaxf((h0 - mn0) * sc0 + bt0, 0.f);
        h1 = fmaxf((h1 - mn1) * sc1 + bt1, 0.f);
        *(float2*)(hout + (size_t)v * 128 + c) = make_float2(h0, h1);
    }
}

// ---------------------------------------------------------------------------
// K7: final classifier: z = relu(BN0(cls_acc)); out = z @ W1 + b1
__global__ __launch_bounds__(256) void classifier_final_kernel(
    const float* __restrict__ acc,
    const float* __restrict__ g, const float* __restrict__ bt,
    const float* __restrict__ mn, const float* __restrict__ vr,
    const float* __restrict__ W1, const float* __restrict__ b1,
    float* __restrict__ out, int n) {
    __shared__ float W1s[128 * 47];
    __shared__ float zbuf[4][128];
    const int tid = threadIdx.x, lane = tid & 63, wid = tid >> 6;
    for (int idx = tid; idx < 128 * 47; idx += 256) W1s[idx] = W1[idx];
    __syncthreads();

    const int c0 = lane * 2;
    const float sc0 = g[c0] * rsqrtf(vr[c0] + EPS);
    const float sc1 = g[c0 + 1] * rsqrtf(vr[c0 + 1] + EPS);
    const float m0 = mn[c0], m1 = mn[c0 + 1];
    const float be0 = bt[c0], be1 = bt[c0 + 1];
    const float bb = (lane < 47) ? b1[lane] : 0.f;

    const int gw = blockIdx.x * 4 + wid;
    const int nw = gridDim.x * 4;
    for (int row = gw; row < n; row += nw) {
        float2 a = *(const float2*)(acc + (size_t)row * 128 + c0);
        zbuf[wid][c0]     = fmaxf((a.x - m0) * sc0 + be0, 0.f);
        zbuf[wid][c0 + 1] = fmaxf((a.y - m1) * sc1 + be1, 0.f);
        float o = 0.f;
        if (lane < 47) {
            #pragma unroll 8
            for (int k = 0; k < 128; ++k) o += zbuf[wid][k] * W1s[k * 47 + lane];
            out[(size_t)row * 47 + lane] = o + bb;
        }
    }
}

// ---------------------------------------------------------------------------
extern "C" void kernel_launch(void* const* d_in, const int* in_sizes, int n_in,
                              void* d_out, int out_size, void* d_ws, size_t ws_size,
                              hipStream_t stream) {
    const float* feat     = (const float*)d_in[0];
    const int*   src      = (const int*)d_in[1];
    const int*   dst      = (const int*)d_in[2];
    const float* enc_W    = (const float*)d_in[3];
    const float* enc_bias = (const float*)d_in[4];
    const float* bn_gamma = (const float*)d_in[5];
    const float* bn_beta  = (const float*)d_in[6];
    const float* bn_mean  = (const float*)d_in[7];
    const float* bn_var   = (const float*)d_in[8];
    const float* cls_W0   = (const float*)d_in[9];
    const float* cls_b0   = (const float*)d_in[10];
    const float* cls_g0   = (const float*)d_in[11];
    const float* cls_be0  = (const float*)d_in[12];
    const float* cls_m0   = (const float*)d_in[13];
    const float* cls_v0   = (const float*)d_in[14];
    const float* cls_W1   = (const float*)d_in[15];
    const float* cls_b1   = (const float*)d_in[16];
    float* out = (float*)d_out;

    const int N_ = in_sizes[0] / 128;
    const int E_ = in_sizes[1];

    char* p = (char*)d_ws;
    auto alloc = [&](size_t bytes) {
        char* r = p;
        p += (bytes + 255) & ~(size_t)255;
        return r;
    };
    float* h_a      = (float*)alloc((size_t)N_ * 128 * 4);
    float* h_b      = (float*)alloc((size_t)N_ * 128 * 4);
    float* cls_acc  = (float*)alloc((size_t)N_ * 128 * 4);
    float* norm_src = (float*)alloc((size_t)N_ * 4);
    float* norm_dst = (float*)alloc((size_t)N_ * 4);
    int* outdeg     = (int*)alloc((size_t)N_ * 4);
    int* indeg      = (int*)alloc((size_t)N_ * 4);
    int* offs       = (int*)alloc((size_t)(N_ + 1) * 4);
    int* csc        = (int*)alloc((size_t)E_ * 4);
    int* rank       = (int*)alloc((size_t)E_ * 4);
    int* bsums      = (int*)alloc(256 * 4);

    hipMemsetAsync(outdeg, 0, (size_t)N_ * 4, stream);
    hipMemsetAsync(indeg, 0, (size_t)N_ * 4, stream);

    const int eb = (E_ + 255) / 256;
    const int nb = (N_ + 1023) / 1024;   // <=64 required by scan_bsums
    degrees_kernel<<<eb, 256, 0, stream>>>(src, dst, outdeg, indeg, rank, E_);
    norms_kernel<<<(N_ + 255) / 256, 256, 0, stream>>>(outdeg, indeg, norm_src, norm_dst, N_);
    scan_partial_kernel<<<nb, 256, 0, stream>>>(indeg, bsums, N_);
    scan_bsums_kernel<<<1, 64, 0, stream>>>(bsums, offs, nb, N_);
    scan_final_kernel<<<nb, 256, 0, stream>>>(indeg, bsums, offs, N_);
    fill_csc_kernel<<<eb, 256, 0, stream>>>(src, dst, offs, rank, csc, E_);

    const int gblocks = (N_ + 127) / 128;
    const int agg_blocks = (N_ + 3) / 4;

    for (int i = 0; i < 4; ++i) {
        const float* hin = (i == 0) ? feat : h_a;
        gemm128_kernel<<<gblocks, 256, 0, stream>>>(
            hin, enc_W + (size_t)i * 128 * 128, h_b, norm_src, nullptr, N_, 0);
        aggregate_kernel<<<agg_blocks, 256, 0, stream>>>(
            h_b, offs, csc, norm_dst,
            (i == 3) ? enc_bias : nullptr,
            bn_gamma + i * 128, bn_beta + i * 128, bn_mean + i * 128, bn_var + i * 128,
            h_a, N_);
        gemm128_kernel<<<gblocks, 256, 0, stream>>>(
            h_a, cls_W0 + (size_t)i * 128 * 128, cls_acc, nullptr,
            (i == 0) ? cls_b0 : nullptr, N_, (i == 0) ? 0 : 1);
    }
    classifier_final_kernel<<<(N_ + 15) / 16, 256, 0, stream>>>(
        cls_acc, cls_g0, cls_be0, cls_m0, cls_v0, cls_W1, cls_b1, out, N_);
}

// Round 4
// 511.633 us; speedup vs baseline: 10.9270x; 1.2181x over previous
//
#include <hip/hip_runtime.h>
#include <hip/hip_bf16.h>

#define EPS 1e-5f

typedef __attribute__((ext_vector_type(8))) short short8;
typedef __attribute__((ext_vector_type(4))) float f32x4;

__device__ __forceinline__ unsigned short f2bf_rn(float f) {
    unsigned u = __builtin_bit_cast(unsigned, f);
    u += 0x7fffu + ((u >> 16) & 1u);
    return (unsigned short)(u >> 16);
}
__device__ __forceinline__ float bf2f(unsigned short h) {
    return __builtin_bit_cast(float, (unsigned)h << 16);
}

// ---------------------------------------------------------------------------
// K1: degree histograms + per-edge arrival rank at dst (old atomic value)
__global__ void degrees_kernel(const int* __restrict__ src, const int* __restrict__ dst,
                               int* __restrict__ outdeg, int* __restrict__ indeg,
                               int* __restrict__ rank, int E) {
    int i = blockIdx.x * blockDim.x + threadIdx.x;
    if (i < E) {
        atomicAdd(&outdeg[src[i]], 1);
        rank[i] = atomicAdd(&indeg[dst[i]], 1);
    }
}

// K2: normalization factors rsqrt(max(deg,1))
__global__ void norms_kernel(const int* __restrict__ outdeg, const int* __restrict__ indeg,
                             float* __restrict__ nsrc, float* __restrict__ ndst, int n) {
    int i = blockIdx.x * blockDim.x + threadIdx.x;
    if (i < n) {
        nsrc[i] = rsqrtf((float)max(outdeg[i], 1));
        ndst[i] = rsqrtf((float)max(indeg[i], 1));
    }
}

// ---------------------------------------------------------------------------
// Multi-block exclusive scan of in-degrees -> CSC offsets
__global__ __launch_bounds__(256) void scan_partial_kernel(const int* __restrict__ deg,
                                                           int* __restrict__ bsums, int n) {
    __shared__ int wsum[4];
    const int tid = threadIdx.x, lane = tid & 63, wid = tid >> 6;
    const int i0 = blockIdx.x * 1024 + tid * 4;
    int s = 0;
    if (i0 + 3 < n) {
        int4 v = *(const int4*)(deg + i0);
        s = v.x + v.y + v.z + v.w;
    } else {
        for (int j = 0; j < 4; ++j) if (i0 + j < n) s += deg[i0 + j];
    }
    #pragma unroll
    for (int off = 32; off >= 1; off >>= 1) s += __shfl_down(s, off, 64);
    if (lane == 0) wsum[wid] = s;
    __syncthreads();
    if (tid == 0) bsums[blockIdx.x] = wsum[0] + wsum[1] + wsum[2] + wsum[3];
}

__global__ __launch_bounds__(64) void scan_bsums_kernel(int* __restrict__ bsums,
                                                        int* __restrict__ offs, int nb, int n) {
    int lane = threadIdx.x;
    int v = (lane < nb) ? bsums[lane] : 0;
    int x = v;
    #pragma unroll
    for (int off = 1; off < 64; off <<= 1) {
        int t = __shfl_up(x, off, 64);
        if (lane >= off) x += t;
    }
    if (lane < nb) bsums[lane] = x - v;
    if (lane == 63) offs[n] = x;
}

__global__ __launch_bounds__(256) void scan_final_kernel(const int* __restrict__ deg,
                                                         const int* __restrict__ bsums,
                                                         int* __restrict__ offs, int n) {
    __shared__ int wsum[4];
    const int tid = threadIdx.x, lane = tid & 63, wid = tid >> 6;
    const int i0 = blockIdx.x * 1024 + tid * 4;
    int d0 = 0, d1 = 0, d2 = 0, d3 = 0;
    if (i0 + 3 < n) {
        int4 v = *(const int4*)(deg + i0);
        d0 = v.x; d1 = v.y; d2 = v.z; d3 = v.w;
    } else {
        if (i0 + 0 < n) d0 = deg[i0 + 0];
        if (i0 + 1 < n) d1 = deg[i0 + 1];
        if (i0 + 2 < n) d2 = deg[i0 + 2];
        if (i0 + 3 < n) d3 = deg[i0 + 3];
    }
    int s = d0 + d1 + d2 + d3;
    int x = s;
    #pragma unroll
    for (int off = 1; off < 64; off <<= 1) {
        int t = __shfl_up(x, off, 64);
        if (lane >= off) x += t;
    }
    if (lane == 63) wsum[wid] = x;
    __syncthreads();
    int wpre = 0;
    #pragma unroll
    for (int w = 0; w < 4; ++w) if (w < wid) wpre += wsum[w];
    int base = bsums[blockIdx.x] + wpre + (x - s);
    if (i0 + 0 < n) offs[i0 + 0] = base;
    if (i0 + 1 < n) offs[i0 + 1] = base + d0;
    if (i0 + 2 < n) offs[i0 + 2] = base + d0 + d1;
    if (i0 + 3 < n) offs[i0 + 3] = base + d0 + d1 + d2;
}

// K4: pure scatter using precomputed ranks
__global__ void fill_csc_kernel(const int* __restrict__ src, const int* __restrict__ dst,
                                const int* __restrict__ offs, const int* __restrict__ rank,
                                int* __restrict__ csc, int E) {
    int i = blockIdx.x * blockDim.x + threadIdx.x;
    if (i < E) csc[offs[dst[i]] + rank[i]] = src[i];
}

// ---------------------------------------------------------------------------
// Kp: pack weight matrix B [K][128] row-major into MFMA fragment order,
// bf16 hi/lo planes. Index t = (cf*KF + kf)*64 + lane; lane holds
// B[kf*32 + (lane>>4)*8 + j][cf*16 + (lane&15)], j=0..7.
__global__ void pack_w_kernel(const float* __restrict__ B, short* __restrict__ hi,
                              short* __restrict__ lo, int K, int NCF) {
    int t = blockIdx.x * blockDim.x + threadIdx.x;
    int KF = K >> 5;
    int total = NCF * KF * 64;
    if (t >= total) return;
    int lane = t & 63;
    int kf = (t >> 6) % KF;
    int cf = (t >> 6) / KF;
    int col = cf * 16 + (lane & 15);
    int k0 = kf * 32 + (lane >> 4) * 8;
    int o = t * 8;
    #pragma unroll
    for (int j = 0; j < 8; ++j) {
        float x = B[(size_t)(k0 + j) * 128 + col];
        unsigned short h = f2bf_rn(x);
        hi[o + j] = (short)h;
        lo[o + j] = (short)f2bf_rn(x - bf2f(h));
    }
}

// ---------------------------------------------------------------------------
// K5: MFMA GEMM  C[M,128] = (A[M,128] * rowscale) @ B[128,128]
// bf16x2 split: C = Ahi*Bhi + Alo*Bhi + Ahi*Blo. LDS-free: A-frags direct from
// global (8 consecutive fp32 per lane), B-frags from pre-packed planes (L2-hot).
// Wave computes 32 rows x 128 cols; block = 4 waves = 128 rows.
__global__ __launch_bounds__(256) void mfma_gemm_kernel(
    const float* __restrict__ A, const short* __restrict__ Bhi, const short* __restrict__ Blo,
    const float* __restrict__ rowscale, float* __restrict__ C, int M) {
    const int lane = threadIdx.x & 63;
    const int wid  = threadIdx.x >> 6;
    const int row0 = blockIdx.x * 128 + wid * 32;
    const int rsub = lane & 15;
    const int kg   = lane >> 4;

    short8 ahi[2][4], alo[2][4];
    #pragma unroll
    for (int rf = 0; rf < 2; ++rf) {
        int row = row0 + rf * 16 + rsub;
        bool ok = row < M;
        int rowc = ok ? row : (M - 1);
        float sc = (ok && rowscale) ? rowscale[row] : (ok ? 1.0f : 0.0f);
        if (!rowscale && ok) sc = 1.0f;
        const float* ap = A + (size_t)rowc * 128 + kg * 8;
        #pragma unroll
        for (int kf = 0; kf < 4; ++kf) {
            float4 v0 = *(const float4*)(ap + kf * 32);
            float4 v1 = *(const float4*)(ap + kf * 32 + 4);
            float v[8] = {v0.x, v0.y, v0.z, v0.w, v1.x, v1.y, v1.z, v1.w};
            short8 h, l;
            #pragma unroll
            for (int j = 0; j < 8; ++j) {
                float x = v[j] * sc;            // sc==0 masks OOB rows
                unsigned short hb = f2bf_rn(x);
                h[j] = (short)hb;
                l[j] = (short)f2bf_rn(x - bf2f(hb));
            }
            ahi[rf][kf] = h; alo[rf][kf] = l;
        }
    }

    f32x4 acc[2][8];
    #pragma unroll
    for (int rf = 0; rf < 2; ++rf)
        #pragma unroll
        for (int cf = 0; cf < 8; ++cf) acc[rf][cf] = (f32x4){0.f, 0.f, 0.f, 0.f};

    #pragma unroll
    for (int cf = 0; cf < 8; ++cf) {
        #pragma unroll
        for (int kf = 0; kf < 4; ++kf) {
            int bidx = ((cf * 4 + kf) * 64 + lane) * 8;
            short8 bh = *(const short8*)(Bhi + bidx);
            short8 bl = *(const short8*)(Blo + bidx);
            #pragma unroll
            for (int rf = 0; rf < 2; ++rf) {
                acc[rf][cf] = __builtin_amdgcn_mfma_f32_16x16x32_bf16(ahi[rf][kf], bh, acc[rf][cf], 0, 0, 0);
                acc[rf][cf] = __builtin_amdgcn_mfma_f32_16x16x32_bf16(alo[rf][kf], bh, acc[rf][cf], 0, 0, 0);
                acc[rf][cf] = __builtin_amdgcn_mfma_f32_16x16x32_bf16(ahi[rf][kf], bl, acc[rf][cf], 0, 0, 0);
            }
        }
    }

    // C/D layout: col = lane&15, row = (lane>>4)*4 + reg
    #pragma unroll
    for (int rf = 0; rf < 2; ++rf)
        #pragma unroll
        for (int r = 0; r < 4; ++r) {
            int row = row0 + rf * 16 + kg * 4 + r;
            if (row < M) {
                float* cp = C + (size_t)row * 128 + rsub;
                #pragma unroll
                for (int cf = 0; cf < 8; ++cf) cp[cf * 16] = acc[rf][cf][r];
            }
        }
}

// ---------------------------------------------------------------------------
// K6: CSC aggregation + norm_dst + (bias) + BN + ReLU. One wave per dst node.
__global__ __launch_bounds__(256) void aggregate_kernel(
    const float* __restrict__ hw, const int* __restrict__ offs, const int* __restrict__ csc,
    const float* __restrict__ norm_dst, const float* __restrict__ bias,
    const float* __restrict__ gamma, const float* __restrict__ beta,
    const float* __restrict__ mean, const float* __restrict__ var,
    float* __restrict__ hout, int n) {
    const int lane = threadIdx.x & 63;
    const int gw = (blockIdx.x * blockDim.x + threadIdx.x) >> 6;
    const int nw = (gridDim.x * blockDim.x) >> 6;
    const int c = lane * 2;

    const float sc0 = gamma[c] * rsqrtf(var[c] + EPS);
    const float sc1 = gamma[c + 1] * rsqrtf(var[c + 1] + EPS);
    const float mn0 = mean[c], mn1 = mean[c + 1];
    const float bt0 = beta[c], bt1 = beta[c + 1];
    const float bi0 = bias ? bias[c] : 0.f;
    const float bi1 = bias ? bias[c + 1] : 0.f;

    for (int v = gw; v < n; v += nw) {
        int e0 = offs[v], e1 = offs[v + 1];
        float2 acc = make_float2(0.f, 0.f);
        int e = e0;
        for (; e + 4 <= e1; e += 4) {
            int s0 = csc[e], s1 = csc[e + 1], s2 = csc[e + 2], s3 = csc[e + 3];
            float2 p0 = *(const float2*)(hw + (size_t)s0 * 128 + c);
            float2 p1 = *(const float2*)(hw + (size_t)s1 * 128 + c);
            float2 p2 = *(const float2*)(hw + (size_t)s2 * 128 + c);
            float2 p3 = *(const float2*)(hw + (size_t)s3 * 128 + c);
            acc.x += (p0.x + p1.x) + (p2.x + p3.x);
            acc.y += (p0.y + p1.y) + (p2.y + p3.y);
        }
        for (; e < e1; ++e) {
            int s0 = csc[e];
            float2 p0 = *(const float2*)(hw + (size_t)s0 * 128 + c);
            acc.x += p0.x; acc.y += p0.y;
        }
        float nd = norm_dst[v];
        float h0 = acc.x * nd + bi0;
        float h1 = acc.y * nd + bi1;
        h0 = fmaxf((h0 - mn0) * sc0 + bt0, 0.f);
        h1 = fmaxf((h1 - mn1) * sc1 + bt1, 0.f);
        *(float2*)(hout + (size_t)v * 128 + c) = make_float2(h0, h1);
    }
}

// ---------------------------------------------------------------------------
// K7: fused classifier: acc = concat(h1..h4) @ W0 (MFMA, bf16x2 split, K=512)
//     z = relu(BN(acc + b0)); out = z @ W1 + b1 (VALU, z in LDS bf16)
__global__ __launch_bounds__(256) void classifier_kernel(
    const float* __restrict__ h1, const float* __restrict__ h2,
    const float* __restrict__ h3, const float* __restrict__ h4,
    const short* __restrict__ Bhi, const short* __restrict__ Blo,
    const float* __restrict__ b0,
    const float* __restrict__ g, const float* __restrict__ bt,
    const float* __restrict__ mn, const float* __restrict__ vr,
    const float* __restrict__ W1, const float* __restrict__ b1,
    float* __restrict__ out, int M) {
    __shared__ float W1s[128 * 47];
    __shared__ unsigned short zs[4][32][130];
    const int tid = threadIdx.x, lane = tid & 63, wid = tid >> 6;
    for (int idx = tid; idx < 128 * 47; idx += 256) W1s[idx] = W1[idx];
    __syncthreads();

    const int rsub = lane & 15;
    const int kg   = lane >> 4;
    const int row0 = blockIdx.x * 128 + wid * 32;
    const float* hb[4] = {h1, h2, h3, h4};

    f32x4 acc[2][8];
    #pragma unroll
    for (int rf = 0; rf < 2; ++rf)
        #pragma unroll
        for (int cf = 0; cf < 8; ++cf) acc[rf][cf] = (f32x4){0.f, 0.f, 0.f, 0.f};

    for (int kf16 = 0; kf16 < 16; ++kf16) {
        const float* H = hb[kf16 >> 2];
        const int koff = (kf16 & 3) * 32 + kg * 8;
        short8 ahi[2], alo[2];
        #pragma unroll
        for (int rf = 0; rf < 2; ++rf) {
            int row = row0 + rf * 16 + rsub;
            bool ok = row < M;
            int rowc = ok ? row : (M - 1);
            const float* ap = H + (size_t)rowc * 128 + koff;
            float4 v0 = *(const float4*)(ap);
            float4 v1 = *(const float4*)(ap + 4);
            float v[8] = {v0.x, v0.y, v0.z, v0.w, v1.x, v1.y, v1.z, v1.w};
            short8 h, l;
            #pragma unroll
            for (int j = 0; j < 8; ++j) {
                float x = ok ? v[j] : 0.f;
                unsigned short hbv = f2bf_rn(x);
                h[j] = (short)hbv;
                l[j] = (short)f2bf_rn(x - bf2f(hbv));
            }
            ahi[rf] = h; alo[rf] = l;
        }
        #pragma unroll
        for (int cf = 0; cf < 8; ++cf) {
            int bidx = ((cf * 16 + kf16) * 64 + lane) * 8;
            short8 bh = *(const short8*)(Bhi + bidx);
            short8 bl = *(const short8*)(Blo + bidx);
            #pragma unroll
            for (int rf = 0; rf < 2; ++rf) {
                acc[rf][cf] = __builtin_amdgcn_mfma_f32_16x16x32_bf16(ahi[rf], bh, acc[rf][cf], 0, 0, 0);
                acc[rf][cf] = __builtin_amdgcn_mfma_f32_16x16x32_bf16(alo[rf], bh, acc[rf][cf], 0, 0, 0);
                acc[rf][cf] = __builtin_amdgcn_mfma_f32_16x16x32_bf16(ahi[rf], bl, acc[rf][cf], 0, 0, 0);
            }
        }
    }

    // bias + BN + ReLU -> z (bf16) into per-wave LDS tile
    #pragma unroll
    for (int cf = 0; cf < 8; ++cf) {
        int col = cf * 16 + rsub;
        float bias = b0[col];
        float scale = g[col] * rsqrtf(vr[col] + EPS);
        float mean = mn[col], beta = bt[col];
        #pragma unroll
        for (int rf = 0; rf < 2; ++rf)
            #pragma unroll
            for (int r = 0; r < 4; ++r) {
                int rl = rf * 16 + kg * 4 + r;
                float z = fmaxf((acc[rf][cf][r] + bias - mean) * scale + beta, 0.f);
                zs[wid][rl][col] = f2bf_rn(z);
            }
    }
    // wave-private LDS tile: in-wave ds ordering via waitcnt, no barrier needed

    const float bb = (lane < 47) ? b1[lane] : 0.f;
    for (int rl = 0; rl < 32; ++rl) {
        int row = row0 + rl;
        if (row >= M) break;
        if (lane < 47) {
            float o = 0.f;
            #pragma unroll 8
            for (int k = 0; k < 128; ++k)
                o += bf2f(zs[wid][rl][k]) * W1s[k * 47 + lane];
            out[(size_t)row * 47 + lane] = o + bb;
        }
    }
}

// ---------------------------------------------------------------------------
extern "C" void kernel_launch(void* const* d_in, const int* in_sizes, int n_in,
                              void* d_out, int out_size, void* d_ws, size_t ws_size,
                              hipStream_t stream) {
    const float* feat     = (const float*)d_in[0];
    const int*   src      = (const int*)d_in[1];
    const int*   dst      = (const int*)d_in[2];
    const float* enc_W    = (const float*)d_in[3];
    const float* enc_bias = (const float*)d_in[4];
    const float* bn_gamma = (const float*)d_in[5];
    const float* bn_beta  = (const float*)d_in[6];
    const float* bn_mean  = (const float*)d_in[7];
    const float* bn_var   = (const float*)d_in[8];
    const float* cls_W0   = (const float*)d_in[9];
    const float* cls_b0   = (const float*)d_in[10];
    const float* cls_g0   = (const float*)d_in[11];
    const float* cls_be0  = (const float*)d_in[12];
    const float* cls_m0   = (const float*)d_in[13];
    const float* cls_v0   = (const float*)d_in[14];
    const float* cls_W1   = (const float*)d_in[15];
    const float* cls_b1   = (const float*)d_in[16];
    float* out = (float*)d_out;

    const int N_ = in_sizes[0] / 128;
    const int E_ = in_sizes[1];

    char* p = (char*)d_ws;
    auto alloc = [&](size_t bytes) {
        char* r = p;
        p += (bytes + 255) & ~(size_t)255;
        return r;
    };
    float* h_b   = (float*)alloc((size_t)N_ * 128 * 4);   // gemm output (XW)
    float* hl[4];
    for (int i = 0; i < 4; ++i) hl[i] = (float*)alloc((size_t)N_ * 128 * 4);
    float* norm_src = (float*)alloc((size_t)N_ * 4);
    float* norm_dst = (float*)alloc((size_t)N_ * 4);
    int* outdeg = (int*)alloc((size_t)N_ * 4);
    int* indeg  = (int*)alloc((size_t)N_ * 4);
    int* offs   = (int*)alloc((size_t)(N_ + 1) * 4);
    int* csc    = (int*)alloc((size_t)E_ * 4);
    int* rank   = (int*)alloc((size_t)E_ * 4);
    int* bsums  = (int*)alloc(256 * 4);
    // packed weights: enc 4 x (8cf*4kf*64*8)=16384 shorts per plane; cls 65536
    short* encBhi = (short*)alloc(4 * 16384 * 2);
    short* encBlo = (short*)alloc(4 * 16384 * 2);
    short* clsBhi = (short*)alloc(65536 * 2);
    short* clsBlo = (short*)alloc(65536 * 2);

    hipMemsetAsync(outdeg, 0, (size_t)N_ * 4, stream);
    hipMemsetAsync(indeg, 0, (size_t)N_ * 4, stream);

    const int eb = (E_ + 255) / 256;
    const int nb = (N_ + 1023) / 1024;   // <=64 required by scan_bsums
    degrees_kernel<<<eb, 256, 0, stream>>>(src, dst, outdeg, indeg, rank, E_);
    norms_kernel<<<(N_ + 255) / 256, 256, 0, stream>>>(outdeg, indeg, norm_src, norm_dst, N_);
    scan_partial_kernel<<<nb, 256, 0, stream>>>(indeg, bsums, N_);
    scan_bsums_kernel<<<1, 64, 0, stream>>>(bsums, offs, nb, N_);
    scan_final_kernel<<<nb, 256, 0, stream>>>(indeg, bsums, offs, N_);
    fill_csc_kernel<<<eb, 256, 0, stream>>>(src, dst, offs, rank, csc, E_);

    // pack weights (tiny)
    for (int i = 0; i < 4; ++i)
        pack_w_kernel<<<8, 256, 0, stream>>>(enc_W + (size_t)i * 128 * 128,
                                             encBhi + i * 16384, encBlo + i * 16384, 128, 8);
    pack_w_kernel<<<32, 256, 0, stream>>>(cls_W0, clsBhi, clsBlo, 512, 8);

    const int gblocks = (N_ + 127) / 128;
    const int agg_blocks = (N_ + 3) / 4;

    for (int i = 0; i < 4; ++i) {
        const float* hin = (i == 0) ? feat : hl[i - 1];
        mfma_gemm_kernel<<<gblocks, 256, 0, stream>>>(
            hin, encBhi + i * 16384, encBlo + i * 16384, norm_src, h_b, N_);
        aggregate_kernel<<<agg_blocks, 256, 0, stream>>>(
            h_b, offs, csc, norm_dst,
            (i == 3) ? enc_bias : nullptr,
            bn_gamma + i * 128, bn_beta + i * 128, bn_mean + i * 128, bn_var + i * 128,
            hl[i], N_);
    }
    classifier_kernel<<<gblocks, 256, 0, stream>>>(
        hl[0], hl[1], hl[2], hl[3], clsBhi, clsBlo, cls_b0,
        cls_g0, cls_be0, cls_m0, cls_v0, cls_W1, cls_b1, out, N_);
}

// Round 5
// 498.431 us; speedup vs baseline: 11.2164x; 1.0265x over previous
//
#include <hip/hip_runtime.h>
#include <hip/hip_bf16.h>

#define EPS 1e-5f

typedef __attribute__((ext_vector_type(8))) short short8;
typedef __attribute__((ext_vector_type(4))) float f32x4;

__device__ __forceinline__ unsigned short f2bf_rn(float f) {
    unsigned u = __builtin_bit_cast(unsigned, f);
    u += 0x7fffu + ((u >> 16) & 1u);
    return (unsigned short)(u >> 16);
}
__device__ __forceinline__ float bf2f(unsigned short h) {
    return __builtin_bit_cast(float, (unsigned)h << 16);
}

// ---------------------------------------------------------------------------
// K1: degree histograms + per-edge arrival rank at dst (old atomic value)
__global__ void degrees_kernel(const int* __restrict__ src, const int* __restrict__ dst,
                               int* __restrict__ outdeg, int* __restrict__ indeg,
                               int* __restrict__ rank, int E) {
    int i = blockIdx.x * blockDim.x + threadIdx.x;
    if (i < E) {
        atomicAdd(&outdeg[src[i]], 1);
        rank[i] = atomicAdd(&indeg[dst[i]], 1);
    }
}

// K2: normalization factors rsqrt(max(deg,1))
__global__ void norms_kernel(const int* __restrict__ outdeg, const int* __restrict__ indeg,
                             float* __restrict__ nsrc, float* __restrict__ ndst, int n) {
    int i = blockIdx.x * blockDim.x + threadIdx.x;
    if (i < n) {
        nsrc[i] = rsqrtf((float)max(outdeg[i], 1));
        ndst[i] = rsqrtf((float)max(indeg[i], 1));
    }
}

// ---------------------------------------------------------------------------
// Multi-block exclusive scan of in-degrees -> CSC offsets
__global__ __launch_bounds__(256) void scan_partial_kernel(const int* __restrict__ deg,
                                                           int* __restrict__ bsums, int n) {
    __shared__ int wsum[4];
    const int tid = threadIdx.x, lane = tid & 63, wid = tid >> 6;
    const int i0 = blockIdx.x * 1024 + tid * 4;
    int s = 0;
    if (i0 + 3 < n) {
        int4 v = *(const int4*)(deg + i0);
        s = v.x + v.y + v.z + v.w;
    } else {
        for (int j = 0; j < 4; ++j) if (i0 + j < n) s += deg[i0 + j];
    }
    #pragma unroll
    for (int off = 32; off >= 1; off >>= 1) s += __shfl_down(s, off, 64);
    if (lane == 0) wsum[wid] = s;
    __syncthreads();
    if (tid == 0) bsums[blockIdx.x] = wsum[0] + wsum[1] + wsum[2] + wsum[3];
}

__global__ __launch_bounds__(64) void scan_bsums_kernel(int* __restrict__ bsums,
                                                        int* __restrict__ offs, int nb, int n) {
    int lane = threadIdx.x;
    int v = (lane < nb) ? bsums[lane] : 0;
    int x = v;
    #pragma unroll
    for (int off = 1; off < 64; off <<= 1) {
        int t = __shfl_up(x, off, 64);
        if (lane >= off) x += t;
    }
    if (lane < nb) bsums[lane] = x - v;
    if (lane == 63) offs[n] = x;
}

__global__ __launch_bounds__(256) void scan_final_kernel(const int* __restrict__ deg,
                                                         const int* __restrict__ bsums,
                                                         int* __restrict__ offs, int n) {
    __shared__ int wsum[4];
    const int tid = threadIdx.x, lane = tid & 63, wid = tid >> 6;
    const int i0 = blockIdx.x * 1024 + tid * 4;
    int d0 = 0, d1 = 0, d2 = 0, d3 = 0;
    if (i0 + 3 < n) {
        int4 v = *(const int4*)(deg + i0);
        d0 = v.x; d1 = v.y; d2 = v.z; d3 = v.w;
    } else {
        if (i0 + 0 < n) d0 = deg[i0 + 0];
        if (i0 + 1 < n) d1 = deg[i0 + 1];
        if (i0 + 2 < n) d2 = deg[i0 + 2];
        if (i0 + 3 < n) d3 = deg[i0 + 3];
    }
    int s = d0 + d1 + d2 + d3;
    int x = s;
    #pragma unroll
    for (int off = 1; off < 64; off <<= 1) {
        int t = __shfl_up(x, off, 64);
        if (lane >= off) x += t;
    }
    if (lane == 63) wsum[wid] = x;
    __syncthreads();
    int wpre = 0;
    #pragma unroll
    for (int w = 0; w < 4; ++w) if (w < wid) wpre += wsum[w];
    int base = bsums[blockIdx.x] + wpre + (x - s);
    if (i0 + 0 < n) offs[i0 + 0] = base;
    if (i0 + 1 < n) offs[i0 + 1] = base + d0;
    if (i0 + 2 < n) offs[i0 + 2] = base + d0 + d1;
    if (i0 + 3 < n) offs[i0 + 3] = base + d0 + d1 + d2;
}

// K4: pure scatter using precomputed ranks
__global__ void fill_csc_kernel(const int* __restrict__ src, const int* __restrict__ dst,
                                const int* __restrict__ offs, const int* __restrict__ rank,
                                int* __restrict__ csc, int E) {
    int i = blockIdx.x * blockDim.x + threadIdx.x;
    if (i < E) csc[offs[dst[i]] + rank[i]] = src[i];
}

// ---------------------------------------------------------------------------
// Kp: pack weight matrix B [K][ncols] (row stride strideB) into MFMA fragment
// order, bf16 hi/lo planes. Lane holds B[kf*32 + (lane>>4)*8 + j][cf*16 + (lane&15)]
// (0 if col >= ncols), j = 0..7. Fragment index = (cf*KF + kf).
__global__ void pack_w_kernel(const float* __restrict__ B, short* __restrict__ hi,
                              short* __restrict__ lo, int K, int NCF,
                              int strideB, int ncols) {
    int t = blockIdx.x * blockDim.x + threadIdx.x;
    int KF = K >> 5;
    int total = NCF * KF * 64;
    if (t >= total) return;
    int lane = t & 63;
    int kf = (t >> 6) % KF;
    int cf = (t >> 6) / KF;
    int col = cf * 16 + (lane & 15);
    int k0 = kf * 32 + (lane >> 4) * 8;
    int o = t * 8;
    #pragma unroll
    for (int j = 0; j < 8; ++j) {
        float x = (col < ncols) ? B[(size_t)(k0 + j) * strideB + col] : 0.f;
        unsigned short h = f2bf_rn(x);
        hi[o + j] = (short)h;
        lo[o + j] = (short)f2bf_rn(x - bf2f(h));
    }
}

// ---------------------------------------------------------------------------
// K5: MFMA GEMM  C[M,128] = (A[M,128] * rowscale) @ B[128,128]
// bf16x2 split: C = Ahi*Bhi + Alo*Bhi + Ahi*Blo. LDS-free.
__global__ __launch_bounds__(256) void mfma_gemm_kernel(
    const float* __restrict__ A, const short* __restrict__ Bhi, const short* __restrict__ Blo,
    const float* __restrict__ rowscale, float* __restrict__ C, int M) {
    const int lane = threadIdx.x & 63;
    const int wid  = threadIdx.x >> 6;
    const int row0 = blockIdx.x * 128 + wid * 32;
    const int rsub = lane & 15;
    const int kg   = lane >> 4;

    short8 ahi[2][4], alo[2][4];
    #pragma unroll
    for (int rf = 0; rf < 2; ++rf) {
        int row = row0 + rf * 16 + rsub;
        bool ok = row < M;
        int rowc = ok ? row : (M - 1);
        float sc = (ok && rowscale) ? rowscale[row] : (ok ? 1.0f : 0.0f);
        if (!rowscale && ok) sc = 1.0f;
        const float* ap = A + (size_t)rowc * 128 + kg * 8;
        #pragma unroll
        for (int kf = 0; kf < 4; ++kf) {
            float4 v0 = *(const float4*)(ap + kf * 32);
            float4 v1 = *(const float4*)(ap + kf * 32 + 4);
            float v[8] = {v0.x, v0.y, v0.z, v0.w, v1.x, v1.y, v1.z, v1.w};
            short8 h, l;
            #pragma unroll
            for (int j = 0; j < 8; ++j) {
                float x = v[j] * sc;            // sc==0 masks OOB rows
                unsigned short hb = f2bf_rn(x);
                h[j] = (short)hb;
                l[j] = (short)f2bf_rn(x - bf2f(hb));
            }
            ahi[rf][kf] = h; alo[rf][kf] = l;
        }
    }

    f32x4 acc[2][8];
    #pragma unroll
    for (int rf = 0; rf < 2; ++rf)
        #pragma unroll
        for (int cf = 0; cf < 8; ++cf) acc[rf][cf] = (f32x4){0.f, 0.f, 0.f, 0.f};

    #pragma unroll
    for (int cf = 0; cf < 8; ++cf) {
        #pragma unroll
        for (int kf = 0; kf < 4; ++kf) {
            int bidx = ((cf * 4 + kf) * 64 + lane) * 8;
            short8 bh = *(const short8*)(Bhi + bidx);
            short8 bl = *(const short8*)(Blo + bidx);
            #pragma unroll
            for (int rf = 0; rf < 2; ++rf) {
                acc[rf][cf] = __builtin_amdgcn_mfma_f32_16x16x32_bf16(ahi[rf][kf], bh, acc[rf][cf], 0, 0, 0);
                acc[rf][cf] = __builtin_amdgcn_mfma_f32_16x16x32_bf16(alo[rf][kf], bh, acc[rf][cf], 0, 0, 0);
                acc[rf][cf] = __builtin_amdgcn_mfma_f32_16x16x32_bf16(ahi[rf][kf], bl, acc[rf][cf], 0, 0, 0);
            }
        }
    }

    // C/D layout: col = lane&15, row = (lane>>4)*4 + reg
    #pragma unroll
    for (int rf = 0; rf < 2; ++rf)
        #pragma unroll
        for (int r = 0; r < 4; ++r) {
            int row = row0 + rf * 16 + kg * 4 + r;
            if (row < M) {
                float* cp = C + (size_t)row * 128 + rsub;
                #pragma unroll
                for (int cf = 0; cf < 8; ++cf) cp[cf * 16] = acc[rf][cf][r];
            }
        }
}

// ---------------------------------------------------------------------------
// K6: CSC aggregation + norm_dst + (bias) + BN + ReLU. One wave per dst node.
__global__ __launch_bounds__(256) void aggregate_kernel(
    const float* __restrict__ hw, const int* __restrict__ offs, const int* __restrict__ csc,
    const float* __restrict__ norm_dst, const float* __restrict__ bias,
    const float* __restrict__ gamma, const float* __restrict__ beta,
    const float* __restrict__ mean, const float* __restrict__ var,
    float* __restrict__ hout, int n) {
    const int lane = threadIdx.x & 63;
    const int gw = (blockIdx.x * blockDim.x + threadIdx.x) >> 6;
    const int nw = (gridDim.x * blockDim.x) >> 6;
    const int c = lane * 2;

    const float sc0 = gamma[c] * rsqrtf(var[c] + EPS);
    const float sc1 = gamma[c + 1] * rsqrtf(var[c + 1] + EPS);
    const float mn0 = mean[c], mn1 = mean[c + 1];
    const float bt0 = beta[c], bt1 = beta[c + 1];
    const float bi0 = bias ? bias[c] : 0.f;
    const float bi1 = bias ? bias[c + 1] : 0.f;

    for (int v = gw; v < n; v += nw) {
        int e0 = offs[v], e1 = offs[v + 1];
        float2 acc = make_float2(0.f, 0.f);
        int e = e0;
        for (; e + 4 <= e1; e += 4) {
            int s0 = csc[e], s1 = csc[e + 1], s2 = csc[e + 2], s3 = csc[e + 3];
            float2 p0 = *(const float2*)(hw + (size_t)s0 * 128 + c);
            float2 p1 = *(const float2*)(hw + (size_t)s1 * 128 + c);
            float2 p2 = *(const float2*)(hw + (size_t)s2 * 128 + c);
            float2 p3 = *(const float2*)(hw + (size_t)s3 * 128 + c);
            acc.x += (p0.x + p1.x) + (p2.x + p3.x);
            acc.y += (p0.y + p1.y) + (p2.y + p3.y);
        }
        for (; e < e1; ++e) {
            int s0 = csc[e];
            float2 p0 = *(const float2*)(hw + (size_t)s0 * 128 + c);
            acc.x += p0.x; acc.y += p0.y;
        }
        float nd = norm_dst[v];
        float h0 = acc.x * nd + bi0;
        float h1 = acc.y * nd + bi1;
        h0 = fmaxf((h0 - mn0) * sc0 + bt0, 0.f);
        h1 = fmaxf((h1 - mn1) * sc1 + bt1, 0.f);
        *(float2*)(hout + (size_t)v * 128 + c) = make_float2(h0, h1);
    }
}

// ---------------------------------------------------------------------------
// K7: fused classifier.
// Stage 1: acc = concat(h1..h4) @ W0 (MFMA bf16x2, K=512)
// Stage 2: z = relu(BN(acc+b0)) -> packed bf16(hi|lo) u32 into swizzled
//          wave-private LDS half-tile -> A-fragments -> MFMA with packed W1.
__global__ __launch_bounds__(256) void classifier_kernel(
    const float* __restrict__ h1, const float* __restrict__ h2,
    const float* __restrict__ h3, const float* __restrict__ h4,
    const short* __restrict__ Bhi, const short* __restrict__ Blo,
    const short* __restrict__ W1hi, const short* __restrict__ W1lo,
    const float* __restrict__ b0,
    const float* __restrict__ g, const float* __restrict__ bt,
    const float* __restrict__ mn, const float* __restrict__ vr,
    const float* __restrict__ b1,
    float* __restrict__ out, int M) {
    __shared__ unsigned int zw[4][16 * 128];   // 32 KB, wave-private half-tiles
    const int tid = threadIdx.x, lane = tid & 63, wid = tid >> 6;
    const int rsub = lane & 15;
    const int kg   = lane >> 4;
    const int row0 = blockIdx.x * 128 + wid * 32;
    const float* hb[4] = {h1, h2, h3, h4};

    // per-lane BN constants for the 8 columns this lane owns (col = cf*16+rsub)
    float biasv[8], scalev[8], meanv[8], betav[8];
    #pragma unroll
    for (int cf = 0; cf < 8; ++cf) {
        int col = cf * 16 + rsub;
        biasv[cf] = b0[col];
        scalev[cf] = g[col] * rsqrtf(vr[col] + EPS);
        meanv[cf] = mn[col];
        betav[cf] = bt[col];
    }

    // ---- stage 1: MFMA over K=512 ----
    f32x4 acc[2][8];
    #pragma unroll
    for (int rf = 0; rf < 2; ++rf)
        #pragma unroll
        for (int cf = 0; cf < 8; ++cf) acc[rf][cf] = (f32x4){0.f, 0.f, 0.f, 0.f};

    for (int kf16 = 0; kf16 < 16; ++kf16) {
        const float* H = hb[kf16 >> 2];
        const int koff = (kf16 & 3) * 32 + kg * 8;
        short8 ahi[2], alo[2];
        #pragma unroll
        for (int rf = 0; rf < 2; ++rf) {
            int row = row0 + rf * 16 + rsub;
            bool ok = row < M;
            int rowc = ok ? row : (M - 1);
            const float* ap = H + (size_t)rowc * 128 + koff;
            float4 v0 = *(const float4*)(ap);
            float4 v1 = *(const float4*)(ap + 4);
            float v[8] = {v0.x, v0.y, v0.z, v0.w, v1.x, v1.y, v1.z, v1.w};
            short8 h, l;
            #pragma unroll
            for (int j = 0; j < 8; ++j) {
                float x = ok ? v[j] : 0.f;
                unsigned short hbv = f2bf_rn(x);
                h[j] = (short)hbv;
                l[j] = (short)f2bf_rn(x - bf2f(hbv));
            }
            ahi[rf] = h; alo[rf] = l;
        }
        #pragma unroll
        for (int cf = 0; cf < 8; ++cf) {
            int bidx = ((cf * 16 + kf16) * 64 + lane) * 8;
            short8 bh = *(const short8*)(Bhi + bidx);
            short8 bl = *(const short8*)(Blo + bidx);
            #pragma unroll
            for (int rf = 0; rf < 2; ++rf) {
                acc[rf][cf] = __builtin_amdgcn_mfma_f32_16x16x32_bf16(ahi[rf], bh, acc[rf][cf], 0, 0, 0);
                acc[rf][cf] = __builtin_amdgcn_mfma_f32_16x16x32_bf16(alo[rf], bh, acc[rf][cf], 0, 0, 0);
                acc[rf][cf] = __builtin_amdgcn_mfma_f32_16x16x32_bf16(ahi[rf], bl, acc[rf][cf], 0, 0, 0);
            }
        }
    }

    // ---- stage 2: per 16-row half-tile: z -> LDS (swizzled) -> MFMA with W1 ----
    f32x4 oacc[2][3];
    #pragma unroll
    for (int rf = 0; rf < 2; ++rf)
        #pragma unroll
        for (int cf = 0; cf < 3; ++cf) oacc[rf][cf] = (f32x4){0.f, 0.f, 0.f, 0.f};

    #pragma unroll
    for (int rf = 0; rf < 2; ++rf) {
        // write z for local rows 0..15 of this half (acc reg layout: row=kg*4+r, col=cf*16+rsub)
        #pragma unroll
        for (int cf = 0; cf < 8; ++cf) {
            int col = cf * 16 + rsub;
            #pragma unroll
            for (int r = 0; r < 4; ++r) {
                int rloc = kg * 4 + r;
                float z = fmaxf((acc[rf][cf][r] + biasv[cf] - meanv[cf]) * scalev[cf] + betav[cf], 0.f);
                unsigned short h = f2bf_rn(z);
                unsigned short l = f2bf_rn(z - bf2f(h));
                zw[wid][rloc * 128 + (col ^ ((rloc & 7) << 2))] = ((unsigned)h << 16) | l;
            }
        }
        // wave-private tile: in-wave DS ordering (compiler waits lgkmcnt), no barrier
        const int rloc = rsub;
        const int s = (rloc & 7) << 2;
        #pragma unroll
        for (int kf = 0; kf < 4; ++kf) {
            int k0 = kf * 32 + kg * 8;
            uint4 ua = *(const uint4*)&zw[wid][rloc * 128 + (k0 ^ s)];
            uint4 ub = *(const uint4*)&zw[wid][rloc * 128 + ((k0 + 4) ^ s)];
            unsigned uu[8] = {ua.x, ua.y, ua.z, ua.w, ub.x, ub.y, ub.z, ub.w};
            short8 zh, zl;
            #pragma unroll
            for (int j = 0; j < 8; ++j) {
                zh[j] = (short)(uu[j] >> 16);
                zl[j] = (short)(uu[j] & 0xffffu);
            }
            #pragma unroll
            for (int cf = 0; cf < 3; ++cf) {
                int bidx = ((cf * 4 + kf) * 64 + lane) * 8;
                short8 wh = *(const short8*)(W1hi + bidx);
                short8 wl = *(const short8*)(W1lo + bidx);
                oacc[rf][cf] = __builtin_amdgcn_mfma_f32_16x16x32_bf16(zh, wh, oacc[rf][cf], 0, 0, 0);
                oacc[rf][cf] = __builtin_amdgcn_mfma_f32_16x16x32_bf16(zl, wh, oacc[rf][cf], 0, 0, 0);
                oacc[rf][cf] = __builtin_amdgcn_mfma_f32_16x16x32_bf16(zh, wl, oacc[rf][cf], 0, 0, 0);
            }
        }
    }

    // store: D layout col = lane&15, row = (lane>>4)*4 + reg
    #pragma unroll
    for (int rf = 0; rf < 2; ++rf)
        #pragma unroll
        for (int cf = 0; cf < 3; ++cf) {
            int col = cf * 16 + rsub;
            if (col < 47) {
                float bb = b1[col];
                #pragma unroll
                for (int r = 0; r < 4; ++r) {
                    int row = row0 + rf * 16 + kg * 4 + r;
                    if (row < M) out[(size_t)row * 47 + col] = oacc[rf][cf][r] + bb;
                }
            }
        }
}

// ---------------------------------------------------------------------------
extern "C" void kernel_launch(void* const* d_in, const int* in_sizes, int n_in,
                              void* d_out, int out_size, void* d_ws, size_t ws_size,
                              hipStream_t stream) {
    const float* feat     = (const float*)d_in[0];
    const int*   src      = (const int*)d_in[1];
    const int*   dst      = (const int*)d_in[2];
    const float* enc_W    = (const float*)d_in[3];
    const float* enc_bias = (const float*)d_in[4];
    const float* bn_gamma = (const float*)d_in[5];
    const float* bn_beta  = (const float*)d_in[6];
    const float* bn_mean  = (const float*)d_in[7];
    const float* bn_var   = (const float*)d_in[8];
    const float* cls_W0   = (const float*)d_in[9];
    const float* cls_b0   = (const float*)d_in[10];
    const float* cls_g0   = (const float*)d_in[11];
    const float* cls_be0  = (const float*)d_in[12];
    const float* cls_m0   = (const float*)d_in[13];
    const float* cls_v0   = (const float*)d_in[14];
    const float* cls_W1   = (const float*)d_in[15];
    const float* cls_b1   = (const float*)d_in[16];
    float* out = (float*)d_out;

    const int N_ = in_sizes[0] / 128;
    const int E_ = in_sizes[1];

    char* p = (char*)d_ws;
    auto alloc = [&](size_t bytes) {
        char* r = p;
        p += (bytes + 255) & ~(size_t)255;
        return r;
    };
    float* h_b   = (float*)alloc((size_t)N_ * 128 * 4);   // gemm output (XW)
    float* hl[4];
    for (int i = 0; i < 4; ++i) hl[i] = (float*)alloc((size_t)N_ * 128 * 4);
    float* norm_src = (float*)alloc((size_t)N_ * 4);
    float* norm_dst = (float*)alloc((size_t)N_ * 4);
    int* outdeg = (int*)alloc((size_t)N_ * 4);
    int* indeg  = (int*)alloc((size_t)N_ * 4);
    int* offs   = (int*)alloc((size_t)(N_ + 1) * 4);
    int* csc    = (int*)alloc((size_t)E_ * 4);
    int* rank   = (int*)alloc((size_t)E_ * 4);
    int* bsums  = (int*)alloc(256 * 4);
    // packed weights: enc 4 x 16384 shorts/plane; cls_W0 65536; W1 6144
    short* encBhi = (short*)alloc(4 * 16384 * 2);
    short* encBlo = (short*)alloc(4 * 16384 * 2);
    short* clsBhi = (short*)alloc(65536 * 2);
    short* clsBlo = (short*)alloc(65536 * 2);
    short* w1hi   = (short*)alloc(6144 * 2);
    short* w1lo   = (short*)alloc(6144 * 2);

    hipMemsetAsync(outdeg, 0, (size_t)N_ * 4, stream);
    hipMemsetAsync(indeg, 0, (size_t)N_ * 4, stream);

    const int eb = (E_ + 255) / 256;
    const int nb = (N_ + 1023) / 1024;   // <=64 required by scan_bsums
    degrees_kernel<<<eb, 256, 0, stream>>>(src, dst, outdeg, indeg, rank, E_);
    norms_kernel<<<(N_ + 255) / 256, 256, 0, stream>>>(outdeg, indeg, norm_src, norm_dst, N_);
    scan_partial_kernel<<<nb, 256, 0, stream>>>(indeg, bsums, N_);
    scan_bsums_kernel<<<1, 64, 0, stream>>>(bsums, offs, nb, N_);
    scan_final_kernel<<<nb, 256, 0, stream>>>(indeg, bsums, offs, N_);
    fill_csc_kernel<<<eb, 256, 0, stream>>>(src, dst, offs, rank, csc, E_);

    // pack weights (tiny)
    for (int i = 0; i < 4; ++i)
        pack_w_kernel<<<8, 256, 0, stream>>>(enc_W + (size_t)i * 128 * 128,
                                             encBhi + i * 16384, encBlo + i * 16384,
                                             128, 8, 128, 128);
    pack_w_kernel<<<32, 256, 0, stream>>>(cls_W0, clsBhi, clsBlo, 512, 8, 128, 128);
    pack_w_kernel<<<3, 256, 0, stream>>>(cls_W1, w1hi, w1lo, 128, 3, 47, 47);

    const int gblocks = (N_ + 127) / 128;
    const int agg_blocks = (N_ + 3) / 4;

    for (int i = 0; i < 4; ++i) {
        const float* hin = (i == 0) ? feat : hl[i - 1];
        mfma_gemm_kernel<<<gblocks, 256, 0, stream>>>(
            hin, encBhi + i * 16384, encBlo + i * 16384, norm_src, h_b, N_);
        aggregate_kernel<<<agg_blocks, 256, 0, stream>>>(
            h_b, offs, csc, norm_dst,
            (i == 3) ? enc_bias : nullptr,
            bn_gamma + i * 128, bn_beta + i * 128, bn_mean + i * 128, bn_var + i * 128,
            hl[i], N_);
    }
    classifier_kernel<<<gblocks, 256, 0, stream>>>(
        hl[0], hl[1], hl[2], hl[3], clsBhi, clsBlo, w1hi, w1lo, cls_b0,
        cls_g0, cls_be0, cls_m0, cls_v0, cls_b1, out, N_);
}

// Round 6
// 408.678 us; speedup vs baseline: 13.6797x; 1.2196x over previous
//
#include <hip/hip_runtime.h>
#include <hip/hip_bf16.h>
#include <hip/hip_fp16.h>

#define EPS 1e-5f
#define HB 32          // histogram blocks
#define HRANGE 25600   // nodes per fill range-pass (u32 cursors: 100KB LDS)
#define NN2 51200      // 2*HRANGE >= N

typedef __attribute__((ext_vector_type(8))) short short8;
typedef __attribute__((ext_vector_type(4))) float f32x4;

__device__ __forceinline__ unsigned short f2bf_rn(float f) {
    unsigned u = __builtin_bit_cast(unsigned, f);
    u += 0x7fffu + ((u >> 16) & 1u);
    return (unsigned short)(u >> 16);
}
__device__ __forceinline__ float bf2f(unsigned short h) {
    return __builtin_bit_cast(float, (unsigned)h << 16);
}

// ---------------------------------------------------------------------------
// K1: per-block LDS histograms (u16-packed pairs), no global atomics.
// arr 0 = dst (indeg), arr 1 = src (outdeg). histW[(arr*HB+b)*HRANGE + j]
// packs counts of nodes 2j (low16) and 2j+1 (high16).
__global__ __launch_bounds__(1024) void hist_kernel(
    const int* __restrict__ src, const int* __restrict__ dst,
    unsigned* __restrict__ histW, int E, int EperB) {
    __shared__ unsigned cnt[HRANGE];
    const int b = blockIdx.x, tid = threadIdx.x;
    const long e0 = (long)b * EperB;
    const long e1 = min(e0 + (long)EperB, (long)E);
    #pragma unroll 2
    for (int arr = 0; arr < 2; ++arr) {
        const int* a = arr ? src : dst;
        for (int j = tid; j < HRANGE; j += 1024) cnt[j] = 0;
        __syncthreads();
        for (long e = e0 + tid; e < e1; e += 1024) {
            int v = a[e];
            atomicAdd(&cnt[v >> 1], 1u << ((v & 1) << 4));
        }
        __syncthreads();
        unsigned* o = histW + ((size_t)(arr * HB + b)) * HRANGE;
        for (int j = tid; j < HRANGE; j += 1024) o[j] = cnt[j];
        __syncthreads();
    }
}

// K2: merge per-block hists -> indeg, norms, and per-(block,node) exclusive
// prefix bp16 (u16) for deterministic-capacity CSC fill.
__global__ __launch_bounds__(256) void merge_kernel(
    const unsigned short* __restrict__ hist16, int* __restrict__ indeg,
    unsigned short* __restrict__ bp16, float* __restrict__ nsrc,
    float* __restrict__ ndst, int N) {
    int n = blockIdx.x * blockDim.x + threadIdx.x;
    if (n >= NN2) return;
    unsigned s = 0;
    #pragma unroll 8
    for (int b = 0; b < HB; ++b) {
        unsigned c = hist16[(size_t)b * NN2 + n];
        bp16[(size_t)b * NN2 + n] = (unsigned short)s;
        s += c;
    }
    unsigned s2 = 0;
    #pragma unroll 8
    for (int b = 0; b < HB; ++b) s2 += hist16[(size_t)(HB + b) * NN2 + n];
    if (n < N) {
        indeg[n] = (int)s;
        ndst[n] = rsqrtf((float)max((int)s, 1));
        nsrc[n] = rsqrtf((float)max((int)s2, 1));
    }
}

// ---------------------------------------------------------------------------
// Multi-block exclusive scan of in-degrees -> CSC offsets
__global__ __launch_bounds__(256) void scan_partial_kernel(const int* __restrict__ deg,
                                                           int* __restrict__ bsums, int n) {
    __shared__ int wsum[4];
    const int tid = threadIdx.x, lane = tid & 63, wid = tid >> 6;
    const int i0 = blockIdx.x * 1024 + tid * 4;
    int s = 0;
    if (i0 + 3 < n) {
        int4 v = *(const int4*)(deg + i0);
        s = v.x + v.y + v.z + v.w;
    } else {
        for (int j = 0; j < 4; ++j) if (i0 + j < n) s += deg[i0 + j];
    }
    #pragma unroll
    for (int off = 32; off >= 1; off >>= 1) s += __shfl_down(s, off, 64);
    if (lane == 0) wsum[wid] = s;
    __syncthreads();
    if (tid == 0) bsums[blockIdx.x] = wsum[0] + wsum[1] + wsum[2] + wsum[3];
}

__global__ __launch_bounds__(64) void scan_bsums_kernel(int* __restrict__ bsums,
                                                        int* __restrict__ offs, int nb, int n) {
    int lane = threadIdx.x;
    int v = (lane < nb) ? bsums[lane] : 0;
    int x = v;
    #pragma unroll
    for (int off = 1; off < 64; off <<= 1) {
        int t = __shfl_up(x, off, 64);
        if (lane >= off) x += t;
    }
    if (lane < nb) bsums[lane] = x - v;
    if (lane == 63) offs[n] = x;
}

__global__ __launch_bounds__(256) void scan_final_kernel(const int* __restrict__ deg,
                                                         const int* __restrict__ bsums,
                                                         int* __restrict__ offs, int n) {
    __shared__ int wsum[4];
    const int tid = threadIdx.x, lane = tid & 63, wid = tid >> 6;
    const int i0 = blockIdx.x * 1024 + tid * 4;
    int d0 = 0, d1 = 0, d2 = 0, d3 = 0;
    if (i0 + 3 < n) {
        int4 v = *(const int4*)(deg + i0);
        d0 = v.x; d1 = v.y; d2 = v.z; d3 = v.w;
    } else {
        if (i0 + 0 < n) d0 = deg[i0 + 0];
        if (i0 + 1 < n) d1 = deg[i0 + 1];
        if (i0 + 2 < n) d2 = deg[i0 + 2];
        if (i0 + 3 < n) d3 = deg[i0 + 3];
    }
    int s = d0 + d1 + d2 + d3;
    int x = s;
    #pragma unroll
    for (int off = 1; off < 64; off <<= 1) {
        int t = __shfl_up(x, off, 64);
        if (lane >= off) x += t;
    }
    if (lane == 63) wsum[wid] = x;
    __syncthreads();
    int wpre = 0;
    #pragma unroll
    for (int w = 0; w < 4; ++w) if (w < wid) wpre += wsum[w];
    int base = bsums[blockIdx.x] + wpre + (x - s);
    if (i0 + 0 < n) offs[i0 + 0] = base;
    if (i0 + 1 < n) offs[i0 + 1] = base + d0;
    if (i0 + 2 < n) offs[i0 + 2] = base + d0 + d1;
    if (i0 + 3 < n) offs[i0 + 3] = base + d0 + d1 + d2;
}

// K4: CSC fill with LDS cursors seeded from offs + per-block prefix.
// Two range passes (u32 cursors, 100KB LDS). No global atomics.
__global__ __launch_bounds__(1024) void fill_kernel(
    const int* __restrict__ src, const int* __restrict__ dst,
    const int* __restrict__ offs, const unsigned short* __restrict__ bp16,
    int* __restrict__ csc, int E, int EperB, int N) {
    __shared__ unsigned cur[HRANGE];
    const int b = blockIdx.x, tid = threadIdx.x;
    const long e0 = (long)b * EperB;
    const long e1 = min(e0 + (long)EperB, (long)E);
    for (int r = 0; r < 2; ++r) {
        const int base = r * HRANGE;
        for (int j = tid; j < HRANGE; j += 1024) {
            int n = base + j;
            cur[j] = (n < N) ? (unsigned)offs[n] + (unsigned)bp16[(size_t)b * NN2 + n] : 0u;
        }
        __syncthreads();
        for (long e = e0 + tid; e < e1; e += 1024) {
            int d = dst[e];
            if (d >= base && d < base + HRANGE) {
                unsigned p = atomicAdd(&cur[d - base], 1u);  // LDS atomic
                csc[p] = src[e];
            }
        }
        __syncthreads();
    }
}

// ---------------------------------------------------------------------------
// Kp: pack weights into MFMA fragment order, bf16 hi/lo planes.
__global__ void pack_w_kernel(const float* __restrict__ B, short* __restrict__ hi,
                              short* __restrict__ lo, int K, int NCF,
                              int strideB, int ncols) {
    int t = blockIdx.x * blockDim.x + threadIdx.x;
    int KF = K >> 5;
    int total = NCF * KF * 64;
    if (t >= total) return;
    int lane = t & 63;
    int kf = (t >> 6) % KF;
    int cf = (t >> 6) / KF;
    int col = cf * 16 + (lane & 15);
    int k0 = kf * 32 + (lane >> 4) * 8;
    int o = t * 8;
    #pragma unroll
    for (int j = 0; j < 8; ++j) {
        float x = (col < ncols) ? B[(size_t)(k0 + j) * strideB + col] : 0.f;
        unsigned short h = f2bf_rn(x);
        hi[o + j] = (short)h;
        lo[o + j] = (short)f2bf_rn(x - bf2f(h));
    }
}

// ---------------------------------------------------------------------------
// K5: MFMA GEMM  C[M,128] (fp16) = (A[M,128] * rowscale) @ B[128,128]
// bf16x2 split, LDS-free.
__global__ __launch_bounds__(256) void mfma_gemm_kernel(
    const float* __restrict__ A, const short* __restrict__ Bhi, const short* __restrict__ Blo,
    const float* __restrict__ rowscale, __half* __restrict__ C, int M) {
    const int lane = threadIdx.x & 63;
    const int wid  = threadIdx.x >> 6;
    const int row0 = blockIdx.x * 128 + wid * 32;
    const int rsub = lane & 15;
    const int kg   = lane >> 4;

    short8 ahi[2][4], alo[2][4];
    #pragma unroll
    for (int rf = 0; rf < 2; ++rf) {
        int row = row0 + rf * 16 + rsub;
        bool ok = row < M;
        int rowc = ok ? row : (M - 1);
        float sc = ok ? (rowscale ? rowscale[row] : 1.0f) : 0.0f;
        const float* ap = A + (size_t)rowc * 128 + kg * 8;
        #pragma unroll
        for (int kf = 0; kf < 4; ++kf) {
            float4 v0 = *(const float4*)(ap + kf * 32);
            float4 v1 = *(const float4*)(ap + kf * 32 + 4);
            float v[8] = {v0.x, v0.y, v0.z, v0.w, v1.x, v1.y, v1.z, v1.w};
            short8 h, l;
            #pragma unroll
            for (int j = 0; j < 8; ++j) {
                float x = v[j] * sc;
                unsigned short hb = f2bf_rn(x);
                h[j] = (short)hb;
                l[j] = (short)f2bf_rn(x - bf2f(hb));
            }
            ahi[rf][kf] = h; alo[rf][kf] = l;
        }
    }

    f32x4 acc[2][8];
    #pragma unroll
    for (int rf = 0; rf < 2; ++rf)
        #pragma unroll
        for (int cf = 0; cf < 8; ++cf) acc[rf][cf] = (f32x4){0.f, 0.f, 0.f, 0.f};

    #pragma unroll
    for (int cf = 0; cf < 8; ++cf) {
        #pragma unroll
        for (int kf = 0; kf < 4; ++kf) {
            int bidx = ((cf * 4 + kf) * 64 + lane) * 8;
            short8 bh = *(const short8*)(Bhi + bidx);
            short8 bl = *(const short8*)(Blo + bidx);
            #pragma unroll
            for (int rf = 0; rf < 2; ++rf) {
                acc[rf][cf] = __builtin_amdgcn_mfma_f32_16x16x32_bf16(ahi[rf][kf], bh, acc[rf][cf], 0, 0, 0);
                acc[rf][cf] = __builtin_amdgcn_mfma_f32_16x16x32_bf16(alo[rf][kf], bh, acc[rf][cf], 0, 0, 0);
                acc[rf][cf] = __builtin_amdgcn_mfma_f32_16x16x32_bf16(ahi[rf][kf], bl, acc[rf][cf], 0, 0, 0);
            }
        }
    }

    // C/D layout: col = lane&15, row = (lane>>4)*4 + reg
    #pragma unroll
    for (int rf = 0; rf < 2; ++rf)
        #pragma unroll
        for (int r = 0; r < 4; ++r) {
            int row = row0 + rf * 16 + kg * 4 + r;
            if (row < M) {
                __half* cp = C + (size_t)row * 128 + rsub;
                #pragma unroll
                for (int cf = 0; cf < 8; ++cf) cp[cf * 16] = __float2half(acc[rf][cf][r]);
            }
        }
}

// ---------------------------------------------------------------------------
// K6: CSC aggregation (fp16 gather) + norm_dst + (bias) + BN + ReLU.
// One wave per dst node; lane covers 2 cols (half2 = 4B -> 256B/row/wave).
__global__ __launch_bounds__(256) void aggregate_kernel(
    const __half* __restrict__ hw, const int* __restrict__ offs, const int* __restrict__ csc,
    const float* __restrict__ norm_dst, const float* __restrict__ bias,
    const float* __restrict__ gamma, const float* __restrict__ beta,
    const float* __restrict__ mean, const float* __restrict__ var,
    float* __restrict__ hout, int n) {
    const int lane = threadIdx.x & 63;
    const int gw = (blockIdx.x * blockDim.x + threadIdx.x) >> 6;
    const int nw = (gridDim.x * blockDim.x) >> 6;
    const int c = lane * 2;

    const float sc0 = gamma[c] * rsqrtf(var[c] + EPS);
    const float sc1 = gamma[c + 1] * rsqrtf(var[c + 1] + EPS);
    const float mn0 = mean[c], mn1 = mean[c + 1];
    const float bt0 = beta[c], bt1 = beta[c + 1];
    const float bi0 = bias ? bias[c] : 0.f;
    const float bi1 = bias ? bias[c + 1] : 0.f;

    for (int v = gw; v < n; v += nw) {
        int e0 = offs[v], e1 = offs[v + 1];
        float2 acc = make_float2(0.f, 0.f);
        int e = e0;
        for (; e + 4 <= e1; e += 4) {
            int s0 = csc[e], s1 = csc[e + 1], s2 = csc[e + 2], s3 = csc[e + 3];
            float2 p0 = __half22float2(*(const __half2*)(hw + (size_t)s0 * 128 + c));
            float2 p1 = __half22float2(*(const __half2*)(hw + (size_t)s1 * 128 + c));
            float2 p2 = __half22float2(*(const __half2*)(hw + (size_t)s2 * 128 + c));
            float2 p3 = __half22float2(*(const __half2*)(hw + (size_t)s3 * 128 + c));
            acc.x += (p0.x + p1.x) + (p2.x + p3.x);
            acc.y += (p0.y + p1.y) + (p2.y + p3.y);
        }
        for (; e < e1; ++e) {
            int s0 = csc[e];
            float2 p0 = __half22float2(*(const __half2*)(hw + (size_t)s0 * 128 + c));
            acc.x += p0.x; acc.y += p0.y;
        }
        float nd = norm_dst[v];
        float h0 = acc.x * nd + bi0;
        float h1 = acc.y * nd + bi1;
        h0 = fmaxf((h0 - mn0) * sc0 + bt0, 0.f);
        h1 = fmaxf((h1 - mn1) * sc1 + bt1, 0.f);
        *(float2*)(hout + (size_t)v * 128 + c) = make_float2(h0, h1);
    }
}

// ---------------------------------------------------------------------------
// K7: fused classifier (stage1 MFMA K=512, stage2 MFMA via swizzled LDS)
__global__ __launch_bounds__(256) void classifier_kernel(
    const float* __restrict__ h1, const float* __restrict__ h2,
    const float* __restrict__ h3, const float* __restrict__ h4,
    const short* __restrict__ Bhi, const short* __restrict__ Blo,
    const short* __restrict__ W1hi, const short* __restrict__ W1lo,
    const float* __restrict__ b0,
    const float* __restrict__ g, const float* __restrict__ bt,
    const float* __restrict__ mn, const float* __restrict__ vr,
    const float* __restrict__ b1,
    float* __restrict__ out, int M) {
    __shared__ unsigned int zw[4][16 * 128];
    const int tid = threadIdx.x, lane = tid & 63, wid = tid >> 6;
    const int rsub = lane & 15;
    const int kg   = lane >> 4;
    const int row0 = blockIdx.x * 128 + wid * 32;
    const float* hb[4] = {h1, h2, h3, h4};

    float biasv[8], scalev[8], meanv[8], betav[8];
    #pragma unroll
    for (int cf = 0; cf < 8; ++cf) {
        int col = cf * 16 + rsub;
        biasv[cf] = b0[col];
        scalev[cf] = g[col] * rsqrtf(vr[col] + EPS);
        meanv[cf] = mn[col];
        betav[cf] = bt[col];
    }

    f32x4 acc[2][8];
    #pragma unroll
    for (int rf = 0; rf < 2; ++rf)
        #pragma unroll
        for (int cf = 0; cf < 8; ++cf) acc[rf][cf] = (f32x4){0.f, 0.f, 0.f, 0.f};

    for (int kf16 = 0; kf16 < 16; ++kf16) {
        const float* H = hb[kf16 >> 2];
        const int koff = (kf16 & 3) * 32 + kg * 8;
        short8 ahi[2], alo[2];
        #pragma unroll
        for (int rf = 0; rf < 2; ++rf) {
            int row = row0 + rf * 16 + rsub;
            bool ok = row < M;
            int rowc = ok ? row : (M - 1);
            const float* ap = H + (size_t)rowc * 128 + koff;
            float4 v0 = *(const float4*)(ap);
            float4 v1 = *(const float4*)(ap + 4);
            float v[8] = {v0.x, v0.y, v0.z, v0.w, v1.x, v1.y, v1.z, v1.w};
            short8 h, l;
            #pragma unroll
            for (int j = 0; j < 8; ++j) {
                float x = ok ? v[j] : 0.f;
                unsigned short hbv = f2bf_rn(x);
                h[j] = (short)hbv;
                l[j] = (short)f2bf_rn(x - bf2f(hbv));
            }
            ahi[rf] = h; alo[rf] = l;
        }
        #pragma unroll
        for (int cf = 0; cf < 8; ++cf) {
            int bidx = ((cf * 16 + kf16) * 64 + lane) * 8;
            short8 bh = *(const short8*)(Bhi + bidx);
            short8 bl = *(const short8*)(Blo + bidx);
            #pragma unroll
            for (int rf = 0; rf < 2; ++rf) {
                acc[rf][cf] = __builtin_amdgcn_mfma_f32_16x16x32_bf16(ahi[rf], bh, acc[rf][cf], 0, 0, 0);
                acc[rf][cf] = __builtin_amdgcn_mfma_f32_16x16x32_bf16(alo[rf], bh, acc[rf][cf], 0, 0, 0);
                acc[rf][cf] = __builtin_amdgcn_mfma_f32_16x16x32_bf16(ahi[rf], bl, acc[rf][cf], 0, 0, 0);
            }
        }
    }

    f32x4 oacc[2][3];
    #pragma unroll
    for (int rf = 0; rf < 2; ++rf)
        #pragma unroll
        for (int cf = 0; cf < 3; ++cf) oacc[rf][cf] = (f32x4){0.f, 0.f, 0.f, 0.f};

    #pragma unroll
    for (int rf = 0; rf < 2; ++rf) {
        #pragma unroll
        for (int cf = 0; cf < 8; ++cf) {
            int col = cf * 16 + rsub;
            #pragma unroll
            for (int r = 0; r < 4; ++r) {
                int rloc = kg * 4 + r;
                float z = fmaxf((acc[rf][cf][r] + biasv[cf] - meanv[cf]) * scalev[cf] + betav[cf], 0.f);
                unsigned short h = f2bf_rn(z);
                unsigned short l = f2bf_rn(z - bf2f(h));
                zw[wid][rloc * 128 + (col ^ ((rloc & 7) << 2))] = ((unsigned)h << 16) | l;
            }
        }
        const int rloc = rsub;
        const int s = (rloc & 7) << 2;
        #pragma unroll
        for (int kf = 0; kf < 4; ++kf) {
            int k0 = kf * 32 + kg * 8;
            uint4 ua = *(const uint4*)&zw[wid][rloc * 128 + (k0 ^ s)];
            uint4 ub = *(const uint4*)&zw[wid][rloc * 128 + ((k0 + 4) ^ s)];
            unsigned uu[8] = {ua.x, ua.y, ua.z, ua.w, ub.x, ub.y, ub.z, ub.w};
            short8 zh, zl;
            #pragma unroll
            for (int j = 0; j < 8; ++j) {
                zh[j] = (short)(uu[j] >> 16);
                zl[j] = (short)(uu[j] & 0xffffu);
            }
            #pragma unroll
            for (int cf = 0; cf < 3; ++cf) {
                int bidx = ((cf * 4 + kf) * 64 + lane) * 8;
                short8 wh = *(const short8*)(W1hi + bidx);
                short8 wl = *(const short8*)(W1lo + bidx);
                oacc[rf][cf] = __builtin_amdgcn_mfma_f32_16x16x32_bf16(zh, wh, oacc[rf][cf], 0, 0, 0);
                oacc[rf][cf] = __builtin_amdgcn_mfma_f32_16x16x32_bf16(zl, wh, oacc[rf][cf], 0, 0, 0);
                oacc[rf][cf] = __builtin_amdgcn_mfma_f32_16x16x32_bf16(zh, wl, oacc[rf][cf], 0, 0, 0);
            }
        }
    }

    #pragma unroll
    for (int rf = 0; rf < 2; ++rf)
        #pragma unroll
        for (int cf = 0; cf < 3; ++cf) {
            int col = cf * 16 + rsub;
            if (col < 47) {
                float bb = b1[col];
                #pragma unroll
                for (int r = 0; r < 4; ++r) {
                    int row = row0 + rf * 16 + kg * 4 + r;
                    if (row < M) out[(size_t)row * 47 + col] = oacc[rf][cf][r] + bb;
                }
            }
        }
}

// ---------------------------------------------------------------------------
extern "C" void kernel_launch(void* const* d_in, const int* in_sizes, int n_in,
                              void* d_out, int out_size, void* d_ws, size_t ws_size,
                              hipStream_t stream) {
    const float* feat     = (const float*)d_in[0];
    const int*   src      = (const int*)d_in[1];
    const int*   dst      = (const int*)d_in[2];
    const float* enc_W    = (const float*)d_in[3];
    const float* enc_bias = (const float*)d_in[4];
    const float* bn_gamma = (const float*)d_in[5];
    const float* bn_beta  = (const float*)d_in[6];
    const float* bn_mean  = (const float*)d_in[7];
    const float* bn_var   = (const float*)d_in[8];
    const float* cls_W0   = (const float*)d_in[9];
    const float* cls_b0   = (const float*)d_in[10];
    const float* cls_g0   = (const float*)d_in[11];
    const float* cls_be0  = (const float*)d_in[12];
    const float* cls_m0   = (const float*)d_in[13];
    const float* cls_v0   = (const float*)d_in[14];
    const float* cls_W1   = (const float*)d_in[15];
    const float* cls_b1   = (const float*)d_in[16];
    float* out = (float*)d_out;

    const int N_ = in_sizes[0] / 128;
    const int E_ = in_sizes[1];

    char* p = (char*)d_ws;
    auto alloc = [&](size_t bytes) {
        char* r = p;
        p += (bytes + 255) & ~(size_t)255;
        return r;
    };
    __half* h_b = (__half*)alloc((size_t)N_ * 128 * 2);   // XW product, fp16
    float* hl[4];
    for (int i = 0; i < 4; ++i) hl[i] = (float*)alloc((size_t)N_ * 128 * 4);
    float* norm_src = (float*)alloc((size_t)NN2 * 4);
    float* norm_dst = (float*)alloc((size_t)NN2 * 4);
    int* indeg  = (int*)alloc((size_t)NN2 * 4);
    int* offs   = (int*)alloc((size_t)(N_ + 1) * 4);
    int* csc    = (int*)alloc((size_t)E_ * 4);
    int* bsums  = (int*)alloc(256 * 4);
    unsigned* histW = (unsigned*)alloc((size_t)2 * HB * HRANGE * 4);        // 6.55MB
    unsigned short* bp16 = (unsigned short*)alloc((size_t)HB * NN2 * 2);    // 3.3MB
    short* encBhi = (short*)alloc(4 * 16384 * 2);
    short* encBlo = (short*)alloc(4 * 16384 * 2);
    short* clsBhi = (short*)alloc(65536 * 2);
    short* clsBlo = (short*)alloc(65536 * 2);
    short* w1hi   = (short*)alloc(6144 * 2);
    short* w1lo   = (short*)alloc(6144 * 2);

    const int EperB = (E_ + HB - 1) / HB;
    const int nb = (N_ + 1023) / 1024;   // <=64 required by scan_bsums

    hist_kernel<<<HB, 1024, 0, stream>>>(src, dst, histW, E_, EperB);
    merge_kernel<<<(NN2 + 255) / 256, 256, 0, stream>>>(
        (const unsigned short*)histW, indeg, bp16, norm_src, norm_dst, N_);
    scan_partial_kernel<<<nb, 256, 0, stream>>>(indeg, bsums, N_);
    scan_bsums_kernel<<<1, 64, 0, stream>>>(bsums, offs, nb, N_);
    scan_final_kernel<<<nb, 256, 0, stream>>>(indeg, bsums, offs, N_);
    fill_kernel<<<HB, 1024, 0, stream>>>(src, dst, offs, bp16, csc, E_, EperB, N_);

    for (int i = 0; i < 4; ++i)
        pack_w_kernel<<<8, 256, 0, stream>>>(enc_W + (size_t)i * 128 * 128,
                                             encBhi + i * 16384, encBlo + i * 16384,
                                             128, 8, 128, 128);
    pack_w_kernel<<<32, 256, 0, stream>>>(cls_W0, clsBhi, clsBlo, 512, 8, 128, 128);
    pack_w_kernel<<<3, 256, 0, stream>>>(cls_W1, w1hi, w1lo, 128, 3, 47, 47);

    const int gblocks = (N_ + 127) / 128;
    const int agg_blocks = (N_ + 3) / 4;

    for (int i = 0; i < 4; ++i) {
        const float* hin = (i == 0) ? feat : hl[i - 1];
        mfma_gemm_kernel<<<gblocks, 256, 0, stream>>>(
            hin, encBhi + i * 16384, encBlo + i * 16384, norm_src, h_b, N_);
        aggregate_kernel<<<agg_blocks, 256, 0, stream>>>(
            h_b, offs, csc, norm_dst,
            (i == 3) ? enc_bias : nullptr,
            bn_gamma + i * 128, bn_beta + i * 128, bn_mean + i * 128, bn_var + i * 128,
            hl[i], N_);
    }
    classifier_kernel<<<gblocks, 256, 0, stream>>>(
        hl[0], hl[1], hl[2], hl[3], clsBhi, clsBlo, w1hi, w1lo, cls_b0,
        cls_g0, cls_be0, cls_m0, cls_v0, cls_b1, out, N_);
}